// Round 7
// baseline (293.092 us; speedup 1.0000x reference)
//
#include <hip/hip_runtime.h>
#include <hip/hip_bf16.h>

// ---------------------------------------------------------------------------
// GAT (2 layers) + mean pool + MLP head.
// R5->R6: gemm1+gemm2+al2 fused into one kernel (fused_gemm12). out1 lives
// only in registers: gemm1's swapped-operand D-tile layout (lane=node col,
// 4 consecutive out-cols) IS gemm2's B-fragment layout -- repack is
// xf2[cb>>1][(cb&1)*4+r] = bf16(elu(acc[r]+bias)), lane-local. Kills the
// 51MB out1 round trip + 46MB fragmented store + one dispatch.
// ---------------------------------------------------------------------------

typedef unsigned short u16;
typedef unsigned int u32;
typedef __attribute__((ext_vector_type(8))) short bf16x8;
typedef __attribute__((ext_vector_type(4))) float f32x4;

#define LRELU(v) ((v) > 0.0f ? (v) : 0.2f * (v))
#define ELU(v)   ((v) > 0.0f ? (v) : expm1f(v))

__device__ __forceinline__ u16 f2bf(float f) {
    union { float f; u32 u; } c; c.f = f;
    u32 u = c.u;
    u32 r = (u + 0x7fffu + ((u >> 16) & 1u)) >> 16;
    return (u16)r;
}
__device__ __forceinline__ float bf2f(u16 h) {
    return __uint_as_float(((u32)h) << 16);
}

__device__ __forceinline__ bf16x8 ldfrag(const u16* p) {
    ushort4 c0 = *(const ushort4*)(p);
    ushort4 c1 = *(const ushort4*)(p + 16);
    bf16x8 f;
    f[0] = (short)c0.x; f[1] = (short)c0.y; f[2] = (short)c0.z; f[3] = (short)c0.w;
    f[4] = (short)c1.x; f[5] = (short)c1.y; f[6] = (short)c1.z; f[7] = (short)c1.w;
    return f;
}

// ---- W transposes to bf16 [col][k] ----------------------------------------
__global__ __launch_bounds__(256) void castw_kernel(const float* __restrict__ W1,
                                                    const float* __restrict__ W2,
                                                    u16* __restrict__ W1t,
                                                    u16* __restrict__ W2t) {
    int idx = blockIdx.x * 256 + threadIdx.x;
    if (idx < 512 * 128) {
        int c = idx >> 7, k = idx & 127;
        W1t[idx] = f2bf(W1[(size_t)k * 512 + c]);
    }
    int j = idx - 512 * 128;
    if (j >= 0 && j < 64 * 512) {
        int c = j >> 9, k = j & 511;
        W2t[j] = f2bf(W2[(size_t)k * 64 + c]);
    }
}

// ---- fold W1 with a_src/a_dst: Wa[k][j]; j<4 src head j, j>=4 dst ---------
__global__ __launch_bounds__(256) void wa_kernel(const float* __restrict__ W1,
                                                 const float* __restrict__ a_s,
                                                 const float* __restrict__ a_d,
                                                 float* __restrict__ Wa) {
    int idx = blockIdx.x * 256 + threadIdx.x;   // 0..1023
    int k = idx >> 3, j = idx & 7, h = j & 3;
    const float* a = (j < 4) ? (a_s + h * 128) : (a_d + h * 128);
    const float* wrow = W1 + (size_t)k * 512 + h * 128;
    float s = 0.f;
#pragma unroll 8
    for (int o = 0; o < 128; ++o) s += wrow[o] * a[o];
    Wa[k * 8 + j] = s;
}

// ---- prep_x: xbf = bf16(x)  AND  alS1/alD1 = x @ Wa  (fused, one x pass) --
__global__ __launch_bounds__(256) void prep_x(const float* __restrict__ x,
                                              const float* __restrict__ Wa,
                                              u16* __restrict__ xbf,
                                              float* __restrict__ alS,
                                              float* __restrict__ alD, int Nn) {
    int lane = threadIdx.x & 63;
    int wave = threadIdx.x >> 6;
    float4 ls = *(const float4*)(Wa + lane * 8);
    float4 ld = *(const float4*)(Wa + lane * 8 + 4);
    float4 hs = *(const float4*)(Wa + (lane + 64) * 8);
    float4 hd = *(const float4*)(Wa + (lane + 64) * 8 + 4);
    int n = blockIdx.x * 4 + wave;
    if (n >= Nn) return;
    float x0 = x[(size_t)n * 128 + lane];
    float x1 = x[(size_t)n * 128 + lane + 64];
    xbf[(size_t)n * 128 + lane]      = f2bf(x0);
    xbf[(size_t)n * 128 + lane + 64] = f2bf(x1);
    float r0 = x0 * ls.x + x1 * hs.x;
    float r1 = x0 * ls.y + x1 * hs.y;
    float r2 = x0 * ls.z + x1 * hs.z;
    float r3 = x0 * ls.w + x1 * hs.w;
    float r4 = x0 * ld.x + x1 * hd.x;
    float r5 = x0 * ld.y + x1 * hd.y;
    float r6 = x0 * ld.z + x1 * hd.z;
    float r7 = x0 * ld.w + x1 * hd.w;
#pragma unroll
    for (int off = 32; off; off >>= 1) {
        r0 += __shfl_down(r0, off); r1 += __shfl_down(r1, off);
        r2 += __shfl_down(r2, off); r3 += __shfl_down(r3, off);
        r4 += __shfl_down(r4, off); r5 += __shfl_down(r5, off);
        r6 += __shfl_down(r6, off); r7 += __shfl_down(r7, off);
    }
    if (lane == 0) {
        *(float4*)(alS + (size_t)n * 4) = make_float4(r0, r1, r2, r3);
        *(float4*)(alD + (size_t)n * 4) = make_float4(r4, r5, r6, r7);
    }
}

// ---------------- CSR build ------------------------------------------------
__global__ __launch_bounds__(256) void count_kernel(const int* __restrict__ dst,
                                                    int E, int Nn, int* __restrict__ deg) {
    int e = blockIdx.x * 256 + threadIdx.x;
    if (e >= E + Nn) return;
    int d = (e < E) ? dst[e] : (e - E);
    atomicAdd(&deg[d], 1);
}

__global__ __launch_bounds__(256) void scanA_kernel(const int* __restrict__ deg,
                                                    int* __restrict__ offs,
                                                    int* __restrict__ bsum, int n) {
    __shared__ int sh[256];
    int b = blockIdx.x, t = threadIdx.x;
    int base = b * 2048 + t * 8;
    int v[8]; int s = 0;
#pragma unroll
    for (int j = 0; j < 8; ++j) { int i = base + j; v[j] = (i < n) ? deg[i] : 0; s += v[j]; }
    sh[t] = s;
    __syncthreads();
    for (int off = 1; off < 256; off <<= 1) {
        int u = (t >= off) ? sh[t - off] : 0;
        __syncthreads();
        sh[t] += u;
        __syncthreads();
    }
    int run = sh[t] - s;
    if (t == 255) bsum[b] = sh[255];
#pragma unroll
    for (int j = 0; j < 8; ++j) {
        run += v[j];
        int i = base + j;
        if (i < n) offs[i + 1] = run;
    }
}

__global__ __launch_bounds__(64) void scanB_kernel(int* __restrict__ bsum, int nb) {
    int t = threadIdx.x;
    int v = (t < nb) ? bsum[t] : 0;
#pragma unroll
    for (int off = 1; off < 64; off <<= 1) {
        int u = __shfl_up(v, off);
        if (t >= off) v += u;
    }
    if (t < nb) bsum[t] = v;
}

__global__ __launch_bounds__(256) void scanC_kernel(int* __restrict__ offs,
                                                    const int* __restrict__ bsum, int n) {
    int i = blockIdx.x * 256 + threadIdx.x;
    if (i == 0) offs[0] = 0;
    if (i >= n) return;
    int b = i >> 11;
    if (b > 0) offs[i + 1] += bsum[b - 1];
}

// scatter edges into CSR order, storing src/dst directly (no perm)
__global__ __launch_bounds__(256) void scatter_kernel(const int* __restrict__ src,
                                                      const int* __restrict__ dst,
                                                      int E, int Nn,
                                                      const int* __restrict__ offs,
                                                      int* __restrict__ fill,
                                                      int* __restrict__ sCSR,
                                                      int* __restrict__ dCSR) {
    int e = blockIdx.x * 256 + threadIdx.x;
    if (e >= E + Nn) return;
    int s = (e < E) ? src[e] : (e - E);
    int d = (e < E) ? dst[e] : (e - E);
    int pos = offs[d] + atomicAdd(&fill[d], 1);
    sCSR[pos] = s;
    dCSR[pos] = d;
}

// ---- per-position exp weights (CSR order), layer 1 (H=4) ------------------
__global__ __launch_bounds__(256) void edgew1_kernel(const int* __restrict__ sCSR,
                                                     const int* __restrict__ dCSR,
                                                     int Et,
                                                     const float* __restrict__ alS,
                                                     const float* __restrict__ alD,
                                                     float* __restrict__ wE) {
    int i = blockIdx.x * 256 + threadIdx.x;
    if (i >= Et) return;
    int s = sCSR[i], d = dCSR[i];
    float4 as = *(const float4*)(alS + (size_t)s * 4);
    float4 ad = *(const float4*)(alD + (size_t)d * 4);
    float4 w;
    float t;
    t = as.x + ad.x; w.x = expf(LRELU(t));
    t = as.y + ad.y; w.y = expf(LRELU(t));
    t = as.z + ad.z; w.z = expf(LRELU(t));
    t = as.w + ad.w; w.w = expf(LRELU(t));
    *(float4*)(wE + (size_t)i * 4) = w;
}

// ---- layer-1 aggregate of bf16 x -> bf16 xagg (sequential CSR streams) ----
__global__ __launch_bounds__(64) void aggx_kernel(const u16* __restrict__ xbf,
                                                  const int* __restrict__ sCSR,
                                                  const int* __restrict__ offs,
                                                  const float* __restrict__ wE,
                                                  u16* __restrict__ xagg) {
    int n = blockIdx.x;
    int t = threadIdx.x;               // 2 feats per lane
    float a0x = 0.f, a0y = 0.f, a1x = 0.f, a1y = 0.f;
    float a2x = 0.f, a2y = 0.f, a3x = 0.f, a3y = 0.f;
    float ws0 = 0.f, ws1 = 0.f, ws2 = 0.f, ws3 = 0.f;
    int s0 = offs[n], s1 = offs[n + 1];
    for (int i = s0; i < s1; ++i) {
        int sn = sCSR[i];                                    // broadcast
        float4 w = *(const float4*)(wE + (size_t)i * 4);     // sequential
        u32 u = *(const u32*)(xbf + (size_t)sn * 128 + t * 2);
        float xlo = __uint_as_float(u << 16);
        float xhi = __uint_as_float(u & 0xffff0000u);
        a0x += w.x * xlo; a0y += w.x * xhi;
        a1x += w.y * xlo; a1y += w.y * xhi;
        a2x += w.z * xlo; a2y += w.z * xhi;
        a3x += w.w * xlo; a3y += w.w * xhi;
        ws0 += w.x; ws1 += w.y; ws2 += w.z; ws3 += w.w;
    }
    float i0 = 1.f / ws0, i1 = 1.f / ws1, i2 = 1.f / ws2, i3 = 1.f / ws3;
    u16* o = xagg + (size_t)n * 512 + t * 2;
    *(u32*)(o + 0)   = (u32)f2bf(a0x * i0) | ((u32)f2bf(a0y * i0) << 16);
    *(u32*)(o + 128) = (u32)f2bf(a1x * i1) | ((u32)f2bf(a1y * i1) << 16);
    *(u32*)(o + 256) = (u32)f2bf(a2x * i2) | ((u32)f2bf(a2y * i2) << 16);
    *(u32*)(o + 384) = (u32)f2bf(a3x * i3) | ((u32)f2bf(a3y * i3) << 16);
}

// ---- fused layer-1 GEMM + ELU + layer-2 GEMM + al2 ------------------------
// Wave = 16 nodes. gemm1: for each of 32 col-blocks, D-tile (lane: node=l&15,
// cols cb*16+kg*4+{0..3}) is elu'd, bf16-packed, and stored lane-locally as
// gemm2's B-fragment: xf2[cb>>1][(cb&1)*4+r]. Then gemm2 (K=512, 16 frags)
// + h2 store + fused al2 (partial dots + shfl reduce over kg).
__global__ __launch_bounds__(256) void fused_gemm12(const u16* __restrict__ xagg,
                                                    const u16* __restrict__ W1t,
                                                    const float* __restrict__ b1,
                                                    const u16* __restrict__ W2t,
                                                    const float* __restrict__ a_s2,
                                                    const float* __restrict__ a_d2,
                                                    u16* __restrict__ h2bf,
                                                    float* __restrict__ alS,
                                                    float* __restrict__ alD, int M) {
    int wv = threadIdx.x >> 6, l = threadIdx.x & 63;
    int nb = blockIdx.x * 64 + wv * 16;
    int lrow = l & 15, kg = l >> 4;
    int node = nb + lrow;

    // x fragments, all 4 heads (frag s covers k_global = 32s..32s+31)
    const u16* xr = xagg + (size_t)node * 512 + kg * 4;
    bf16x8 xf[16];
#pragma unroll
    for (int s = 0; s < 16; ++s) xf[s] = ldfrag(xr + s * 32);

    // ---- gemm1: out1 fragments built in registers ----
    bf16x8 xf2[16];
#pragma unroll
    for (int cb = 0; cb < 32; ++cb) {
        int h = cb >> 3;
        const u16* wc = W1t + (size_t)(cb * 16 + lrow) * 128 + kg * 4;
        f32x4 acc = {0.f, 0.f, 0.f, 0.f};
#pragma unroll
        for (int s = 0; s < 4; ++s)
            acc = __builtin_amdgcn_mfma_f32_16x16x32_bf16(ldfrag(wc + s * 32),
                                                          xf[h * 4 + s], acc, 0, 0, 0);
        float4 bias = *(const float4*)(b1 + cb * 16 + kg * 4);
        int s2 = cb >> 1, hi = (cb & 1) * 4;
        float v0 = acc[0] + bias.x, v1 = acc[1] + bias.y;
        float v2 = acc[2] + bias.z, v3 = acc[3] + bias.w;
        xf2[s2][hi + 0] = (short)f2bf(ELU(v0));
        xf2[s2][hi + 1] = (short)f2bf(ELU(v1));
        xf2[s2][hi + 2] = (short)f2bf(ELU(v2));
        xf2[s2][hi + 3] = (short)f2bf(ELU(v3));
    }

    // ---- gemm2 (K=512) + h2 store + al2 partial dots ----
    float ps = 0.f, pd = 0.f;
#pragma unroll
    for (int c2 = 0; c2 < 4; ++c2) {
        int c0 = c2 * 16;
        const u16* wc = W2t + (size_t)(c0 + lrow) * 512 + kg * 4;
        f32x4 acc = {0.f, 0.f, 0.f, 0.f};
#pragma unroll
        for (int s = 0; s < 16; ++s)
            acc = __builtin_amdgcn_mfma_f32_16x16x32_bf16(ldfrag(wc + s * 32),
                                                          xf2[s], acc, 0, 0, 0);
        float4 as = *(const float4*)(a_s2 + c0 + kg * 4);
        float4 ad = *(const float4*)(a_d2 + c0 + kg * 4);
        ps += acc[0] * as.x + acc[1] * as.y + acc[2] * as.z + acc[3] * as.w;
        pd += acc[0] * ad.x + acc[1] * ad.y + acc[2] * ad.z + acc[3] * ad.w;
        if (node < M) {
            ushort4 o;
            o.x = f2bf(acc[0]); o.y = f2bf(acc[1]);
            o.z = f2bf(acc[2]); o.w = f2bf(acc[3]);
            *(ushort4*)(h2bf + (size_t)node * 64 + c0 + kg * 4) = o;
        }
    }
    ps += __shfl_xor(ps, 16); ps += __shfl_xor(ps, 32);
    pd += __shfl_xor(pd, 16); pd += __shfl_xor(pd, 32);
    if (kg == 0 && node < M) { alS[node] = ps; alD[node] = pd; }
}

__global__ __launch_bounds__(256) void edgew2_kernel(const int* __restrict__ sCSR,
                                                     const int* __restrict__ dCSR,
                                                     int Et,
                                                     const float* __restrict__ alS,
                                                     const float* __restrict__ alD,
                                                     float* __restrict__ wE) {
    int i = blockIdx.x * 256 + threadIdx.x;
    if (i >= Et) return;
    int s = sCSR[i], d = dCSR[i];
    float t = alS[s] + alD[d];
    wE[i] = expf(LRELU(t));
}

// ---- layer-2 aggregate (bf16 gather) + bias + ELU -------------------------
__global__ __launch_bounds__(256) void agg2_kernel(const u16* __restrict__ h2bf,
                                                   const int* __restrict__ sCSR,
                                                   const int* __restrict__ offs,
                                                   const float* __restrict__ wE,
                                                   const float* __restrict__ b2,
                                                   float* __restrict__ out2, int Nn) {
    int n = blockIdx.x * 4 + (threadIdx.x >> 6);
    int f = threadIdx.x & 63;
    if (n >= Nn) return;
    float acc = 0.f, wsum = 0.f;
    int s0 = offs[n], s1 = offs[n + 1];
    for (int i = s0; i < s1; ++i) {
        int sn = sCSR[i];
        float w = wE[i];
        wsum += w;
        acc += w * bf2f(h2bf[(size_t)sn * 64 + f]);
    }
    float v = acc / wsum + b2[f];
    out2[(size_t)n * 64 + f] = ELU(v);
}

// ---------------- pool + head ----------------------------------------------
__device__ __forceinline__ int lower_bound_i(const int* arr, int n, int key) {
    int lo = 0, hi = n;
    while (lo < hi) {
        int mid = (lo + hi) >> 1;
        if (arr[mid] < key) lo = mid + 1; else hi = mid;
    }
    return lo;
}

__global__ __launch_bounds__(64) void pool_kernel(const float* __restrict__ h2,
                                                  const int* __restrict__ batch,
                                                  int Nn, float* __restrict__ pooled) {
    int g = blockIdx.x;
    __shared__ int sh[2];
    if (threadIdx.x == 0) sh[0] = lower_bound_i(batch, Nn, g);
    if (threadIdx.x == 1) sh[1] = lower_bound_i(batch, Nn, g + 1);
    __syncthreads();
    int s0 = sh[0], s1 = sh[1];
    float sum = 0.f;
    for (int i = s0; i < s1; ++i) sum += h2[(size_t)i * 64 + threadIdx.x];
    float cnt = (float)((s1 - s0) > 1 ? (s1 - s0) : 1);
    pooled[(size_t)g * 64 + threadIdx.x] = sum / cnt;
}

__global__ __launch_bounds__(64) void fc_kernel(const float* __restrict__ pooled,
                                                const float* __restrict__ w1,
                                                const float* __restrict__ bb1,
                                                const float* __restrict__ w2,
                                                const float* __restrict__ bb2,
                                                float* __restrict__ out) {
    int g = blockIdx.x;
    __shared__ float p[64];
    __shared__ float hid[32];
    int t = threadIdx.x;
    p[t] = pooled[(size_t)g * 64 + t];
    __syncthreads();
    if (t < 32) {
        float a = bb1[t];
#pragma unroll
        for (int k = 0; k < 64; ++k) a += p[k] * w1[k * 32 + t];
        hid[t] = a > 0.f ? a : 0.f;
    }
    __syncthreads();
    if (t == 0) {
        float a = bb2[0];
#pragma unroll
        for (int j = 0; j < 32; ++j) a += hid[j] * w2[j];
        out[g] = 1.0f / (1.0f + expf(-a));
    }
}

// ---------------------------------------------------------------------------
extern "C" void kernel_launch(void* const* d_in, const int* in_sizes, int n_in,
                              void* d_out, int out_size, void* d_ws, size_t ws_size,
                              hipStream_t stream) {
    const float* x      = (const float*)d_in[0];
    const int*   ei     = (const int*)d_in[1];
    const int*   batch  = (const int*)d_in[2];
    const float* W1     = (const float*)d_in[3];
    const float* a_src1 = (const float*)d_in[4];
    const float* a_dst1 = (const float*)d_in[5];
    const float* b1     = (const float*)d_in[6];
    const float* W2     = (const float*)d_in[7];
    const float* a_src2 = (const float*)d_in[8];
    const float* a_dst2 = (const float*)d_in[9];
    const float* b2     = (const float*)d_in[10];
    const float* fcw1   = (const float*)d_in[11];
    const float* fcb1   = (const float*)d_in[12];
    const float* fcw2   = (const float*)d_in[13];
    const float* fcb2   = (const float*)d_in[14];
    float* out = (float*)d_out;

    const int Nn = in_sizes[0] / 128;   // 25000
    const int E  = in_sizes[1] / 2;     // 400000
    const int Et = E + Nn;
    const int NG = out_size;            // 512
    const int* srcA = ei;
    const int* dstA = ei + E;

    char* base = (char*)d_ws;
    size_t off = 0;
    auto alloc = [&](size_t bytes) -> void* {
        void* p = base + off;
        off += (bytes + 255) & ~(size_t)255;
        return p;
    };
    u16*   xbf    = (u16*)alloc((size_t)Nn * 128 * 2);
    u16*   xagg   = (u16*)alloc(((size_t)Nn + 64) * 512 * 2);  // +64 rows tail pad
    u16*   h2bf   = (u16*)alloc((size_t)Nn * 64 * 2);
    float* out2   = (float*)alloc((size_t)Nn * 64 * 4);
    u16*   W1t    = (u16*)alloc(512 * 128 * 2);
    u16*   W2t    = (u16*)alloc(64 * 512 * 2);
    float* Wa     = (float*)alloc(128 * 8 * 4);
    float* alS1   = (float*)alloc((size_t)Nn * 4 * 4);
    float* alD1   = (float*)alloc((size_t)Nn * 4 * 4);
    float* alS2   = (float*)alloc((size_t)Nn * 4);
    float* alD2   = (float*)alloc((size_t)Nn * 4);
    float* wE1    = (float*)alloc((size_t)Et * 4 * 4);
    float* wE2    = (float*)alloc((size_t)Et * 4);
    int*   deg    = (int*)alloc((size_t)2 * Nn * 4);
    int*   fill   = deg + Nn;
    int*   offs   = (int*)alloc((size_t)(Nn + 1) * 4);
    int*   bsum   = (int*)alloc(64 * 4);
    int*   sCSR   = (int*)alloc((size_t)Et * 4);
    int*   dCSR   = (int*)alloc((size_t)Et * 4);
    float* pooled = (float*)alloc((size_t)NG * 64 * 4);
    (void)ws_size; (void)n_in;

    const int EB = (Et + 255) / 256;
    const int NB = (Nn + 2047) / 2048;

    // ---- weight prep + fused x prep ----
    castw_kernel<<<(512 * 128 + 64 * 512 + 255) / 256, 256, 0, stream>>>(W1, W2, W1t, W2t);
    wa_kernel<<<4, 256, 0, stream>>>(W1, a_src1, a_dst1, Wa);
    prep_x<<<(Nn + 3) / 4, 256, 0, stream>>>(x, Wa, xbf, alS1, alD1, Nn);

    // ---- CSR build ----
    hipMemsetAsync(deg, 0, sizeof(int) * 2 * Nn, stream);
    count_kernel<<<EB, 256, 0, stream>>>(dstA, E, Nn, deg);
    scanA_kernel<<<NB, 256, 0, stream>>>(deg, offs, bsum, Nn);
    scanB_kernel<<<1, 64, 0, stream>>>(bsum, NB);
    scanC_kernel<<<(Nn + 255) / 256, 256, 0, stream>>>(offs, bsum, Nn);
    scatter_kernel<<<EB, 256, 0, stream>>>(srcA, dstA, E, Nn, offs, fill, sCSR, dCSR);

    // ---- layer 1 ----
    edgew1_kernel<<<EB, 256, 0, stream>>>(sCSR, dCSR, Et, alS1, alD1, wE1);
    aggx_kernel<<<Nn, 64, 0, stream>>>(xbf, sCSR, offs, wE1, xagg);

    // ---- fused gemm1 + elu + gemm2 + al2 ----
    fused_gemm12<<<(Nn + 63) / 64, 256, 0, stream>>>(xagg, W1t, b1, W2t, a_src2, a_dst2,
                                                     h2bf, alS2, alD2, Nn);

    // ---- layer 2 edge path ----
    edgew2_kernel<<<EB, 256, 0, stream>>>(sCSR, dCSR, Et, alS2, alD2, wE2);
    agg2_kernel<<<(Nn + 3) / 4, 256, 0, stream>>>(h2bf, sCSR, offs, wE2, b2, out2, Nn);

    // ---- pool + head ----
    pool_kernel<<<NG, 64, 0, stream>>>(out2, batch, Nn, pooled);
    fc_kernel<<<NG, 64, 0, stream>>>(pooled, fcw1, fcb1, fcw2, fcb2, out);
}

// Round 8
// 238.691 us; speedup vs baseline: 1.2279x; 1.2279x over previous
//
#include <hip/hip_runtime.h>
#include <hip/hip_bf16.h>

// ---------------------------------------------------------------------------
// GAT (2 layers) + mean pool + MLP head.
// R6->R7: fusion reverted (compiler gave 88 VGPR -> serialized, 98us).
// Instead: MFMA-fragment-NATIVE layouts end-to-end. castw emits W1f/W2f in
// fragment order (wave frag = contiguous 1KB), aggx writes xaggF in B-frag
// order, gemm1 writes out1F in B-frag order (coalesced 16B/lane stores via
// the D->B identity proven in R6), gemm2 reads both contiguously. Fragment
// map (verified R3-R6): lane l elem j -> k = 32s + 16*(j>>2) + 4*(l>>4) + (j&3),
// row/col = l&15.
// ---------------------------------------------------------------------------

typedef unsigned short u16;
typedef unsigned int u32;
typedef __attribute__((ext_vector_type(8))) short bf16x8;
typedef __attribute__((ext_vector_type(4))) float f32x4;

#define LRELU(v) ((v) > 0.0f ? (v) : 0.2f * (v))
#define ELU(v)   ((v) > 0.0f ? (v) : expm1f(v))

__device__ __forceinline__ u16 f2bf(float f) {
    union { float f; u32 u; } c; c.f = f;
    u32 u = c.u;
    u32 r = (u + 0x7fffu + ((u >> 16) & 1u)) >> 16;
    return (u16)r;
}
__device__ __forceinline__ float bf2f(u16 h) {
    return __uint_as_float(((u32)h) << 16);
}
__device__ __forceinline__ u32 packbf(float lo, float hi) {
    return (u32)f2bf(lo) | ((u32)f2bf(hi) << 16);
}

// ---- W -> fragment-order bf16 ---------------------------------------------
// W1f: 128 frags (head*32 + cb*4 + s), each [lane l][elem j]:
//   col = head*128 + cb*16 + (l&15); k = s*32 + 16*(j>>2) + 4*(l>>4) + (j&3)
// W2f: 64 frags (c2*16 + s): col = c2*16 + (l&15); same k map.
__global__ __launch_bounds__(256) void castw_kernel(const float* __restrict__ W1,
                                                    const float* __restrict__ W2,
                                                    u16* __restrict__ W1f,
                                                    u16* __restrict__ W2f) {
    int idx = blockIdx.x * 256 + threadIdx.x;
    if (idx < 65536) {
        int fid = idx >> 9, l = (idx >> 3) & 63, j = idx & 7;
        int head = fid >> 5, cb = (fid >> 2) & 7, s = fid & 3;
        int col = head * 128 + cb * 16 + (l & 15);
        int k = s * 32 + 16 * (j >> 2) + 4 * (l >> 4) + (j & 3);
        W1f[idx] = f2bf(W1[(size_t)k * 512 + col]);
    } else if (idx < 65536 + 32768) {
        int i2 = idx - 65536;
        int fid = i2 >> 9, l = (i2 >> 3) & 63, j = i2 & 7;
        int c2 = fid >> 4, s = fid & 15;
        int col = c2 * 16 + (l & 15);
        int k = s * 32 + 16 * (j >> 2) + 4 * (l >> 4) + (j & 3);
        W2f[i2] = f2bf(W2[(size_t)k * 64 + col]);
    }
}

// ---- fold W1 with a_src/a_dst: Wa[k][j]; j<4 src head j, j>=4 dst ---------
__global__ __launch_bounds__(256) void wa_kernel(const float* __restrict__ W1,
                                                 const float* __restrict__ a_s,
                                                 const float* __restrict__ a_d,
                                                 float* __restrict__ Wa) {
    int idx = blockIdx.x * 256 + threadIdx.x;   // 0..1023
    int k = idx >> 3, j = idx & 7, h = j & 3;
    const float* a = (j < 4) ? (a_s + h * 128) : (a_d + h * 128);
    const float* wrow = W1 + (size_t)k * 512 + h * 128;
    float s = 0.f;
#pragma unroll 8
    for (int o = 0; o < 128; ++o) s += wrow[o] * a[o];
    Wa[k * 8 + j] = s;
}

// ---- prep_x: xbf = bf16(x)  AND  alS1/alD1 = x @ Wa  (fused, one x pass) --
__global__ __launch_bounds__(256) void prep_x(const float* __restrict__ x,
                                              const float* __restrict__ Wa,
                                              u16* __restrict__ xbf,
                                              float* __restrict__ alS,
                                              float* __restrict__ alD, int Nn) {
    int lane = threadIdx.x & 63;
    int wave = threadIdx.x >> 6;
    float4 ls = *(const float4*)(Wa + lane * 8);
    float4 ld = *(const float4*)(Wa + lane * 8 + 4);
    float4 hs = *(const float4*)(Wa + (lane + 64) * 8);
    float4 hd = *(const float4*)(Wa + (lane + 64) * 8 + 4);
    int n = blockIdx.x * 4 + wave;
    if (n >= Nn) return;
    float x0 = x[(size_t)n * 128 + lane];
    float x1 = x[(size_t)n * 128 + lane + 64];
    xbf[(size_t)n * 128 + lane]      = f2bf(x0);
    xbf[(size_t)n * 128 + lane + 64] = f2bf(x1);
    float r0 = x0 * ls.x + x1 * hs.x;
    float r1 = x0 * ls.y + x1 * hs.y;
    float r2 = x0 * ls.z + x1 * hs.z;
    float r3 = x0 * ls.w + x1 * hs.w;
    float r4 = x0 * ld.x + x1 * hd.x;
    float r5 = x0 * ld.y + x1 * hd.y;
    float r6 = x0 * ld.z + x1 * hd.z;
    float r7 = x0 * ld.w + x1 * hd.w;
#pragma unroll
    for (int off = 32; off; off >>= 1) {
        r0 += __shfl_down(r0, off); r1 += __shfl_down(r1, off);
        r2 += __shfl_down(r2, off); r3 += __shfl_down(r3, off);
        r4 += __shfl_down(r4, off); r5 += __shfl_down(r5, off);
        r6 += __shfl_down(r6, off); r7 += __shfl_down(r7, off);
    }
    if (lane == 0) {
        *(float4*)(alS + (size_t)n * 4) = make_float4(r0, r1, r2, r3);
        *(float4*)(alD + (size_t)n * 4) = make_float4(r4, r5, r6, r7);
    }
}

// ---------------- CSR build ------------------------------------------------
__global__ __launch_bounds__(256) void count_kernel(const int* __restrict__ dst,
                                                    int E, int Nn, int* __restrict__ deg) {
    int e = blockIdx.x * 256 + threadIdx.x;
    if (e >= E + Nn) return;
    int d = (e < E) ? dst[e] : (e - E);
    atomicAdd(&deg[d], 1);
}

__global__ __launch_bounds__(256) void scanA_kernel(const int* __restrict__ deg,
                                                    int* __restrict__ offs,
                                                    int* __restrict__ bsum, int n) {
    __shared__ int sh[256];
    int b = blockIdx.x, t = threadIdx.x;
    int base = b * 2048 + t * 8;
    int v[8]; int s = 0;
#pragma unroll
    for (int j = 0; j < 8; ++j) { int i = base + j; v[j] = (i < n) ? deg[i] : 0; s += v[j]; }
    sh[t] = s;
    __syncthreads();
    for (int off = 1; off < 256; off <<= 1) {
        int u = (t >= off) ? sh[t - off] : 0;
        __syncthreads();
        sh[t] += u;
        __syncthreads();
    }
    int run = sh[t] - s;
    if (t == 255) bsum[b] = sh[255];
#pragma unroll
    for (int j = 0; j < 8; ++j) {
        run += v[j];
        int i = base + j;
        if (i < n) offs[i + 1] = run;
    }
}

__global__ __launch_bounds__(64) void scanB_kernel(int* __restrict__ bsum, int nb) {
    int t = threadIdx.x;
    int v = (t < nb) ? bsum[t] : 0;
#pragma unroll
    for (int off = 1; off < 64; off <<= 1) {
        int u = __shfl_up(v, off);
        if (t >= off) v += u;
    }
    if (t < nb) bsum[t] = v;
}

__global__ __launch_bounds__(256) void scanC_kernel(int* __restrict__ offs,
                                                    const int* __restrict__ bsum, int n) {
    int i = blockIdx.x * 256 + threadIdx.x;
    if (i == 0) offs[0] = 0;
    if (i >= n) return;
    int b = i >> 11;
    if (b > 0) offs[i + 1] += bsum[b - 1];
}

// scatter edges into CSR order, storing src/dst directly (no perm)
__global__ __launch_bounds__(256) void scatter_kernel(const int* __restrict__ src,
                                                      const int* __restrict__ dst,
                                                      int E, int Nn,
                                                      const int* __restrict__ offs,
                                                      int* __restrict__ fill,
                                                      int* __restrict__ sCSR,
                                                      int* __restrict__ dCSR) {
    int e = blockIdx.x * 256 + threadIdx.x;
    if (e >= E + Nn) return;
    int s = (e < E) ? src[e] : (e - E);
    int d = (e < E) ? dst[e] : (e - E);
    int pos = offs[d] + atomicAdd(&fill[d], 1);
    sCSR[pos] = s;
    dCSR[pos] = d;
}

// ---- per-position exp weights (CSR order), layer 1 (H=4) ------------------
__global__ __launch_bounds__(256) void edgew1_kernel(const int* __restrict__ sCSR,
                                                     const int* __restrict__ dCSR,
                                                     int Et,
                                                     const float* __restrict__ alS,
                                                     const float* __restrict__ alD,
                                                     float* __restrict__ wE) {
    int i = blockIdx.x * 256 + threadIdx.x;
    if (i >= Et) return;
    int s = sCSR[i], d = dCSR[i];
    float4 as = *(const float4*)(alS + (size_t)s * 4);
    float4 ad = *(const float4*)(alD + (size_t)d * 4);
    float4 w;
    float t;
    t = as.x + ad.x; w.x = expf(LRELU(t));
    t = as.y + ad.y; w.y = expf(LRELU(t));
    t = as.z + ad.z; w.z = expf(LRELU(t));
    t = as.w + ad.w; w.w = expf(LRELU(t));
    *(float4*)(wE + (size_t)i * 4) = w;
}

// ---- layer-1 aggregate of bf16 x -> xaggF in B-fragment order -------------
// Thread t owns feats f0=2t, f0+1 (per head). Both land in the same fragment,
// same lane, adjacent elems j0,j0+1 -> one u32 store per head.
__global__ __launch_bounds__(64) void aggx_kernel(const u16* __restrict__ xbf,
                                                  const int* __restrict__ sCSR,
                                                  const int* __restrict__ offs,
                                                  const float* __restrict__ wE,
                                                  u16* __restrict__ xaggF) {
    int n = blockIdx.x;
    int t = threadIdx.x;               // 2 feats per lane
    float a0x = 0.f, a0y = 0.f, a1x = 0.f, a1y = 0.f;
    float a2x = 0.f, a2y = 0.f, a3x = 0.f, a3y = 0.f;
    float ws0 = 0.f, ws1 = 0.f, ws2 = 0.f, ws3 = 0.f;
    int s0 = offs[n], s1 = offs[n + 1];
    for (int i = s0; i < s1; ++i) {
        int sn = sCSR[i];                                    // broadcast
        float4 w = *(const float4*)(wE + (size_t)i * 4);     // sequential
        u32 u = *(const u32*)(xbf + (size_t)sn * 128 + t * 2);
        float xlo = __uint_as_float(u << 16);
        float xhi = __uint_as_float(u & 0xffff0000u);
        a0x += w.x * xlo; a0y += w.x * xhi;
        a1x += w.y * xlo; a1y += w.y * xhi;
        a2x += w.z * xlo; a2y += w.z * xhi;
        a3x += w.w * xlo; a3y += w.w * xhi;
        ws0 += w.x; ws1 += w.y; ws2 += w.z; ws3 += w.w;
    }
    float i0 = 1.f / ws0, i1 = 1.f / ws1, i2 = 1.f / ws2, i3 = 1.f / ws3;
    // fragment-order address: f0 = 2t
    int group = n >> 4, lrow = n & 15;
    int f0 = t * 2;
    int sl = f0 >> 5;                       // s_local 0..3
    int kg = (f0 >> 2) & 3;
    int j0 = ((f0 >> 4) & 1) * 4 + (f0 & 3);    // even
    size_t base = ((size_t)group * 16 + sl) * 512 + (size_t)(kg * 16 + lrow) * 8 + j0;
    *(u32*)(xaggF + base + 0 * 2048) = packbf(a0x * i0, a0y * i0);
    *(u32*)(xaggF + base + 1 * 2048) = packbf(a1x * i1, a1y * i1);
    *(u32*)(xaggF + base + 2 * 2048) = packbf(a2x * i2, a2y * i2);
    *(u32*)(xaggF + base + 3 * 2048) = packbf(a3x * i3, a3y * i3);
}

// ---- layer-1 GEMM: out1F = elu(xaggF @ W1 + b1), fragment-native ----------
// 1 wave/block, 2 node-groups (32 nodes); grid (ngp/2, 4 heads). All loads
// and stores are contiguous 16B/lane. No guards (buffers padded to ngp).
__global__ __launch_bounds__(64) void gemm1_mfma(const u16* __restrict__ xaggF,
                                                 const u16* __restrict__ W1f,
                                                 const float* __restrict__ b1,
                                                 u16* __restrict__ out1F) {
    int l = threadIdx.x;
    int head = blockIdx.y;
    int g0 = blockIdx.x * 2;
    int kg = l >> 4;

    bf16x8 xf[2][4];
#pragma unroll
    for (int g = 0; g < 2; ++g) {
        const u16* p = xaggF + ((size_t)(g0 + g) * 16 + head * 4) * 512 + l * 8;
#pragma unroll
        for (int s = 0; s < 4; ++s) xf[g][s] = *(const bf16x8*)(p + s * 512);
    }

    const u16* wbase = W1f + (size_t)head * 32 * 512 + l * 8;

#pragma unroll
    for (int cbp = 0; cbp < 4; ++cbp) {
        bf16x8 op0, op1;
#pragma unroll
        for (int par = 0; par < 2; ++par) {
            int cb = cbp * 2 + par;
            bf16x8 wf[4];
#pragma unroll
            for (int s = 0; s < 4; ++s)
                wf[s] = *(const bf16x8*)(wbase + (size_t)(cb * 4 + s) * 512);
            float4 bias = *(const float4*)(b1 + head * 128 + cb * 16 + kg * 4);
#pragma unroll
            for (int g = 0; g < 2; ++g) {
                f32x4 acc = {0.f, 0.f, 0.f, 0.f};
#pragma unroll
                for (int s = 0; s < 4; ++s)
                    acc = __builtin_amdgcn_mfma_f32_16x16x32_bf16(wf[s], xf[g][s],
                                                                  acc, 0, 0, 0);
                float v0 = ELU(acc[0] + bias.x);
                float v1 = ELU(acc[1] + bias.y);
                float v2 = ELU(acc[2] + bias.z);
                float v3 = ELU(acc[3] + bias.w);
                bf16x8& op = g ? op1 : op0;
                if (par == 0) {
                    op[0] = (short)f2bf(v0); op[1] = (short)f2bf(v1);
                    op[2] = (short)f2bf(v2); op[3] = (short)f2bf(v3);
                } else {
                    op[4] = (short)f2bf(v0); op[5] = (short)f2bf(v1);
                    op[6] = (short)f2bf(v2); op[7] = (short)f2bf(v3);
                }
            }
        }
#pragma unroll
        for (int g = 0; g < 2; ++g) {
            u16* op = out1F + ((size_t)(g0 + g) * 16 + head * 4 + cbp) * 512 + l * 8;
            *(bf16x8*)op = g ? op1 : op0;
        }
    }
}

// ---- layer-2 GEMM + fused al2, fragment-native ----------------------------
// 1 wave/block = 1 node-group (16 nodes); K=512 (16 frags).
__global__ __launch_bounds__(64) void gemm2_mfma(const u16* __restrict__ out1F,
                                                 const u16* __restrict__ W2f,
                                                 const float* __restrict__ a_s2,
                                                 const float* __restrict__ a_d2,
                                                 u16* __restrict__ h2bf,
                                                 float* __restrict__ alS,
                                                 float* __restrict__ alD, int M) {
    int l = threadIdx.x;
    int g = blockIdx.x;
    int lrow = l & 15, kg = l >> 4;
    int node = g * 16 + lrow;

    const u16* xp = out1F + (size_t)g * 16 * 512 + l * 8;
    bf16x8 xf[16];
#pragma unroll
    for (int s = 0; s < 16; ++s) xf[s] = *(const bf16x8*)(xp + s * 512);

    const u16* wp = W2f + l * 8;
    float ps = 0.f, pd = 0.f;
#pragma unroll
    for (int c2 = 0; c2 < 4; ++c2) {
        int c0 = c2 * 16;
        f32x4 acc = {0.f, 0.f, 0.f, 0.f};
#pragma unroll
        for (int s = 0; s < 16; ++s) {
            bf16x8 wf = *(const bf16x8*)(wp + (size_t)(c2 * 16 + s) * 512);
            acc = __builtin_amdgcn_mfma_f32_16x16x32_bf16(wf, xf[s], acc, 0, 0, 0);
        }
        float4 as = *(const float4*)(a_s2 + c0 + kg * 4);
        float4 ad = *(const float4*)(a_d2 + c0 + kg * 4);
        ps += acc[0] * as.x + acc[1] * as.y + acc[2] * as.z + acc[3] * as.w;
        pd += acc[0] * ad.x + acc[1] * ad.y + acc[2] * ad.z + acc[3] * ad.w;
        if (node < M) {
            ushort4 o;
            o.x = f2bf(acc[0]); o.y = f2bf(acc[1]);
            o.z = f2bf(acc[2]); o.w = f2bf(acc[3]);
            *(ushort4*)(h2bf + (size_t)node * 64 + c0 + kg * 4) = o;
        }
    }
    ps += __shfl_xor(ps, 16); ps += __shfl_xor(ps, 32);
    pd += __shfl_xor(pd, 16); pd += __shfl_xor(pd, 32);
    if (kg == 0 && node < M) { alS[node] = ps; alD[node] = pd; }
}

__global__ __launch_bounds__(256) void edgew2_kernel(const int* __restrict__ sCSR,
                                                     const int* __restrict__ dCSR,
                                                     int Et,
                                                     const float* __restrict__ alS,
                                                     const float* __restrict__ alD,
                                                     float* __restrict__ wE) {
    int i = blockIdx.x * 256 + threadIdx.x;
    if (i >= Et) return;
    int s = sCSR[i], d = dCSR[i];
    float t = alS[s] + alD[d];
    wE[i] = expf(LRELU(t));
}

// ---- layer-2 aggregate (bf16 gather) + bias + ELU -------------------------
__global__ __launch_bounds__(256) void agg2_kernel(const u16* __restrict__ h2bf,
                                                   const int* __restrict__ sCSR,
                                                   const int* __restrict__ offs,
                                                   const float* __restrict__ wE,
                                                   const float* __restrict__ b2,
                                                   float* __restrict__ out2, int Nn) {
    int n = blockIdx.x * 4 + (threadIdx.x >> 6);
    int f = threadIdx.x & 63;
    if (n >= Nn) return;
    float acc = 0.f, wsum = 0.f;
    int s0 = offs[n], s1 = offs[n + 1];
    for (int i = s0; i < s1; ++i) {
        int sn = sCSR[i];
        float w = wE[i];
        wsum += w;
        acc += w * bf2f(h2bf[(size_t)sn * 64 + f]);
    }
    float v = acc / wsum + b2[f];
    out2[(size_t)n * 64 + f] = ELU(v);
}

// ---------------- pool + head ----------------------------------------------
__device__ __forceinline__ int lower_bound_i(const int* arr, int n, int key) {
    int lo = 0, hi = n;
    while (lo < hi) {
        int mid = (lo + hi) >> 1;
        if (arr[mid] < key) lo = mid + 1; else hi = mid;
    }
    return lo;
}

__global__ __launch_bounds__(64) void pool_kernel(const float* __restrict__ h2,
                                                  const int* __restrict__ batch,
                                                  int Nn, float* __restrict__ pooled) {
    int g = blockIdx.x;
    __shared__ int sh[2];
    if (threadIdx.x == 0) sh[0] = lower_bound_i(batch, Nn, g);
    if (threadIdx.x == 1) sh[1] = lower_bound_i(batch, Nn, g + 1);
    __syncthreads();
    int s0 = sh[0], s1 = sh[1];
    float sum = 0.f;
    for (int i = s0; i < s1; ++i) sum += h2[(size_t)i * 64 + threadIdx.x];
    float cnt = (float)((s1 - s0) > 1 ? (s1 - s0) : 1);
    pooled[(size_t)g * 64 + threadIdx.x] = sum / cnt;
}

__global__ __launch_bounds__(64) void fc_kernel(const float* __restrict__ pooled,
                                                const float* __restrict__ w1,
                                                const float* __restrict__ bb1,
                                                const float* __restrict__ w2,
                                                const float* __restrict__ bb2,
                                                float* __restrict__ out) {
    int g = blockIdx.x;
    __shared__ float p[64];
    __shared__ float hid[32];
    int t = threadIdx.x;
    p[t] = pooled[(size_t)g * 64 + t];
    __syncthreads();
    if (t < 32) {
        float a = bb1[t];
#pragma unroll
        for (int k = 0; k < 64; ++k) a += p[k] * w1[k * 32 + t];
        hid[t] = a > 0.f ? a : 0.f;
    }
    __syncthreads();
    if (t == 0) {
        float a = bb2[0];
#pragma unroll
        for (int j = 0; j < 32; ++j) a += hid[j] * w2[j];
        out[g] = 1.0f / (1.0f + expf(-a));
    }
}

// ---------------------------------------------------------------------------
extern "C" void kernel_launch(void* const* d_in, const int* in_sizes, int n_in,
                              void* d_out, int out_size, void* d_ws, size_t ws_size,
                              hipStream_t stream) {
    const float* x      = (const float*)d_in[0];
    const int*   ei     = (const int*)d_in[1];
    const int*   batch  = (const int*)d_in[2];
    const float* W1     = (const float*)d_in[3];
    const float* a_src1 = (const float*)d_in[4];
    const float* a_dst1 = (const float*)d_in[5];
    const float* b1     = (const float*)d_in[6];
    const float* W2     = (const float*)d_in[7];
    const float* a_src2 = (const float*)d_in[8];
    const float* a_dst2 = (const float*)d_in[9];
    const float* b2     = (const float*)d_in[10];
    const float* fcw1   = (const float*)d_in[11];
    const float* fcb1   = (const float*)d_in[12];
    const float* fcw2   = (const float*)d_in[13];
    const float* fcb2   = (const float*)d_in[14];
    float* out = (float*)d_out;

    const int Nn = in_sizes[0] / 128;   // 25000
    const int E  = in_sizes[1] / 2;     // 400000
    const int Et = E + Nn;
    const int NG = out_size;            // 512
    const int* srcA = ei;
    const int* dstA = ei + E;

    const int ngroups = (Nn + 15) / 16;          // 1563
    const int ngp = (ngroups + 1) & ~1;          // padded even (gemm1: 2 groups/wave)

    char* base = (char*)d_ws;
    size_t off = 0;
    auto alloc = [&](size_t bytes) -> void* {
        void* p = base + off;
        off += (bytes + 255) & ~(size_t)255;
        return p;
    };
    u16*   xbf    = (u16*)alloc((size_t)Nn * 128 * 2);
    u16*   xaggF  = (u16*)alloc((size_t)ngp * 16 * 512 * 2);   // B-frag order
    u16*   out1F  = (u16*)alloc((size_t)ngp * 16 * 512 * 2);   // B-frag order
    u16*   h2bf   = (u16*)alloc((size_t)Nn * 64 * 2);
    float* out2   = (float*)alloc((size_t)Nn * 64 * 4);
    u16*   W1f    = (u16*)alloc(65536 * 2);
    u16*   W2f    = (u16*)alloc(32768 * 2);
    float* Wa     = (float*)alloc(128 * 8 * 4);
    float* alS1   = (float*)alloc((size_t)Nn * 4 * 4);
    float* alD1   = (float*)alloc((size_t)Nn * 4 * 4);
    float* alS2   = (float*)alloc((size_t)Nn * 4);
    float* alD2   = (float*)alloc((size_t)Nn * 4);
    float* wE1    = (float*)alloc((size_t)Et * 4 * 4);
    float* wE2    = (float*)alloc((size_t)Et * 4);
    int*   deg    = (int*)alloc((size_t)2 * Nn * 4);
    int*   fill   = deg + Nn;
    int*   offs   = (int*)alloc((size_t)(Nn + 1) * 4);
    int*   bsum   = (int*)alloc(64 * 4);
    int*   sCSR   = (int*)alloc((size_t)Et * 4);
    int*   dCSR   = (int*)alloc((size_t)Et * 4);
    float* pooled = (float*)alloc((size_t)NG * 64 * 4);
    (void)ws_size; (void)n_in;

    const int EB = (Et + 255) / 256;
    const int NB = (Nn + 2047) / 2048;

    // ---- weight prep + fused x prep ----
    castw_kernel<<<(65536 + 32768 + 255) / 256, 256, 0, stream>>>(W1, W2, W1f, W2f);
    wa_kernel<<<4, 256, 0, stream>>>(W1, a_src1, a_dst1, Wa);
    prep_x<<<(Nn + 3) / 4, 256, 0, stream>>>(x, Wa, xbf, alS1, alD1, Nn);

    // ---- CSR build ----
    hipMemsetAsync(deg, 0, sizeof(int) * 2 * Nn, stream);
    count_kernel<<<EB, 256, 0, stream>>>(dstA, E, Nn, deg);
    scanA_kernel<<<NB, 256, 0, stream>>>(deg, offs, bsum, Nn);
    scanB_kernel<<<1, 64, 0, stream>>>(bsum, NB);
    scanC_kernel<<<(Nn + 255) / 256, 256, 0, stream>>>(offs, bsum, Nn);
    scatter_kernel<<<EB, 256, 0, stream>>>(srcA, dstA, E, Nn, offs, fill, sCSR, dCSR);

    // ---- layer 1 ----
    edgew1_kernel<<<EB, 256, 0, stream>>>(sCSR, dCSR, Et, alS1, alD1, wE1);
    aggx_kernel<<<Nn, 64, 0, stream>>>(xbf, sCSR, offs, wE1, xaggF);
    dim3 g1(ngp / 2, 4);
    gemm1_mfma<<<g1, 64, 0, stream>>>(xaggF, W1f, b1, out1F);

    // ---- layer 2 (al2 fused into gemm2) ----
    gemm2_mfma<<<ngroups, 64, 0, stream>>>(out1F, W2f, a_src2, a_dst2,
                                           h2bf, alS2, alD2, Nn);
    edgew2_kernel<<<EB, 256, 0, stream>>>(sCSR, dCSR, Et, alS2, alD2, wE2);
    agg2_kernel<<<(Nn + 3) / 4, 256, 0, stream>>>(h2bf, sCSR, offs, wE2, b2, out2, Nn);

    // ---- pool + head ----
    pool_kernel<<<NG, 64, 0, stream>>>(out2, batch, Nn, pooled);
    fc_kernel<<<NG, 64, 0, stream>>>(pooled, fcw1, fcb1, fcw2, fcb2, out);
}

// Round 9
// 210.746 us; speedup vs baseline: 1.3907x; 1.1326x over previous
//
#include <hip/hip_runtime.h>
#include <hip/hip_bf16.h>

// ---------------------------------------------------------------------------
// GAT (2 layers) + mean pool + MLP head.
// R7->R8: aggx/agg2 gather loops manually unrolled x4 (4 independent row
// gathers in flight before accumulation) -- both were latency-bound serial
// CSR walks (VALUBusy ~20%, MfmaUtil 0). aggx moved to 4 waves/block.
// Fragment-native GEMM pipeline unchanged from R7.
// ---------------------------------------------------------------------------

typedef unsigned short u16;
typedef unsigned int u32;
typedef __attribute__((ext_vector_type(8))) short bf16x8;
typedef __attribute__((ext_vector_type(4))) float f32x4;

#define LRELU(v) ((v) > 0.0f ? (v) : 0.2f * (v))
#define ELU(v)   ((v) > 0.0f ? (v) : expm1f(v))

__device__ __forceinline__ u16 f2bf(float f) {
    union { float f; u32 u; } c; c.f = f;
    u32 u = c.u;
    u32 r = (u + 0x7fffu + ((u >> 16) & 1u)) >> 16;
    return (u16)r;
}
__device__ __forceinline__ float bf2f(u16 h) {
    return __uint_as_float(((u32)h) << 16);
}
__device__ __forceinline__ u32 packbf(float lo, float hi) {
    return (u32)f2bf(lo) | ((u32)f2bf(hi) << 16);
}

// ---- W -> fragment-order bf16 ---------------------------------------------
__global__ __launch_bounds__(256) void castw_kernel(const float* __restrict__ W1,
                                                    const float* __restrict__ W2,
                                                    u16* __restrict__ W1f,
                                                    u16* __restrict__ W2f) {
    int idx = blockIdx.x * 256 + threadIdx.x;
    if (idx < 65536) {
        int fid = idx >> 9, l = (idx >> 3) & 63, j = idx & 7;
        int head = fid >> 5, cb = (fid >> 2) & 7, s = fid & 3;
        int col = head * 128 + cb * 16 + (l & 15);
        int k = s * 32 + 16 * (j >> 2) + 4 * (l >> 4) + (j & 3);
        W1f[idx] = f2bf(W1[(size_t)k * 512 + col]);
    } else if (idx < 65536 + 32768) {
        int i2 = idx - 65536;
        int fid = i2 >> 9, l = (i2 >> 3) & 63, j = i2 & 7;
        int c2 = fid >> 4, s = fid & 15;
        int col = c2 * 16 + (l & 15);
        int k = s * 32 + 16 * (j >> 2) + 4 * (l >> 4) + (j & 3);
        W2f[i2] = f2bf(W2[(size_t)k * 64 + col]);
    }
}

// ---- fold W1 with a_src/a_dst: Wa[k][j]; j<4 src head j, j>=4 dst ---------
__global__ __launch_bounds__(256) void wa_kernel(const float* __restrict__ W1,
                                                 const float* __restrict__ a_s,
                                                 const float* __restrict__ a_d,
                                                 float* __restrict__ Wa) {
    int idx = blockIdx.x * 256 + threadIdx.x;   // 0..1023
    int k = idx >> 3, j = idx & 7, h = j & 3;
    const float* a = (j < 4) ? (a_s + h * 128) : (a_d + h * 128);
    const float* wrow = W1 + (size_t)k * 512 + h * 128;
    float s = 0.f;
#pragma unroll 8
    for (int o = 0; o < 128; ++o) s += wrow[o] * a[o];
    Wa[k * 8 + j] = s;
}

// ---- prep_x: xbf = bf16(x)  AND  alS1/alD1 = x @ Wa  (fused, one x pass) --
__global__ __launch_bounds__(256) void prep_x(const float* __restrict__ x,
                                              const float* __restrict__ Wa,
                                              u16* __restrict__ xbf,
                                              float* __restrict__ alS,
                                              float* __restrict__ alD, int Nn) {
    int lane = threadIdx.x & 63;
    int wave = threadIdx.x >> 6;
    float4 ls = *(const float4*)(Wa + lane * 8);
    float4 ld = *(const float4*)(Wa + lane * 8 + 4);
    float4 hs = *(const float4*)(Wa + (lane + 64) * 8);
    float4 hd = *(const float4*)(Wa + (lane + 64) * 8 + 4);
    int n = blockIdx.x * 4 + wave;
    if (n >= Nn) return;
    float x0 = x[(size_t)n * 128 + lane];
    float x1 = x[(size_t)n * 128 + lane + 64];
    xbf[(size_t)n * 128 + lane]      = f2bf(x0);
    xbf[(size_t)n * 128 + lane + 64] = f2bf(x1);
    float r0 = x0 * ls.x + x1 * hs.x;
    float r1 = x0 * ls.y + x1 * hs.y;
    float r2 = x0 * ls.z + x1 * hs.z;
    float r3 = x0 * ls.w + x1 * hs.w;
    float r4 = x0 * ld.x + x1 * hd.x;
    float r5 = x0 * ld.y + x1 * hd.y;
    float r6 = x0 * ld.z + x1 * hd.z;
    float r7 = x0 * ld.w + x1 * hd.w;
#pragma unroll
    for (int off = 32; off; off >>= 1) {
        r0 += __shfl_down(r0, off); r1 += __shfl_down(r1, off);
        r2 += __shfl_down(r2, off); r3 += __shfl_down(r3, off);
        r4 += __shfl_down(r4, off); r5 += __shfl_down(r5, off);
        r6 += __shfl_down(r6, off); r7 += __shfl_down(r7, off);
    }
    if (lane == 0) {
        *(float4*)(alS + (size_t)n * 4) = make_float4(r0, r1, r2, r3);
        *(float4*)(alD + (size_t)n * 4) = make_float4(r4, r5, r6, r7);
    }
}

// ---------------- CSR build ------------------------------------------------
__global__ __launch_bounds__(256) void count_kernel(const int* __restrict__ dst,
                                                    int E, int Nn, int* __restrict__ deg) {
    int e = blockIdx.x * 256 + threadIdx.x;
    if (e >= E + Nn) return;
    int d = (e < E) ? dst[e] : (e - E);
    atomicAdd(&deg[d], 1);
}

__global__ __launch_bounds__(256) void scanA_kernel(const int* __restrict__ deg,
                                                    int* __restrict__ offs,
                                                    int* __restrict__ bsum, int n) {
    __shared__ int sh[256];
    int b = blockIdx.x, t = threadIdx.x;
    int base = b * 2048 + t * 8;
    int v[8]; int s = 0;
#pragma unroll
    for (int j = 0; j < 8; ++j) { int i = base + j; v[j] = (i < n) ? deg[i] : 0; s += v[j]; }
    sh[t] = s;
    __syncthreads();
    for (int off = 1; off < 256; off <<= 1) {
        int u = (t >= off) ? sh[t - off] : 0;
        __syncthreads();
        sh[t] += u;
        __syncthreads();
    }
    int run = sh[t] - s;
    if (t == 255) bsum[b] = sh[255];
#pragma unroll
    for (int j = 0; j < 8; ++j) {
        run += v[j];
        int i = base + j;
        if (i < n) offs[i + 1] = run;
    }
}

__global__ __launch_bounds__(64) void scanB_kernel(int* __restrict__ bsum, int nb) {
    int t = threadIdx.x;
    int v = (t < nb) ? bsum[t] : 0;
#pragma unroll
    for (int off = 1; off < 64; off <<= 1) {
        int u = __shfl_up(v, off);
        if (t >= off) v += u;
    }
    if (t < nb) bsum[t] = v;
}

__global__ __launch_bounds__(256) void scanC_kernel(int* __restrict__ offs,
                                                    const int* __restrict__ bsum, int n) {
    int i = blockIdx.x * 256 + threadIdx.x;
    if (i == 0) offs[0] = 0;
    if (i >= n) return;
    int b = i >> 11;
    if (b > 0) offs[i + 1] += bsum[b - 1];
}

// scatter edges into CSR order, storing src/dst directly (no perm)
__global__ __launch_bounds__(256) void scatter_kernel(const int* __restrict__ src,
                                                      const int* __restrict__ dst,
                                                      int E, int Nn,
                                                      const int* __restrict__ offs,
                                                      int* __restrict__ fill,
                                                      int* __restrict__ sCSR,
                                                      int* __restrict__ dCSR) {
    int e = blockIdx.x * 256 + threadIdx.x;
    if (e >= E + Nn) return;
    int s = (e < E) ? src[e] : (e - E);
    int d = (e < E) ? dst[e] : (e - E);
    int pos = offs[d] + atomicAdd(&fill[d], 1);
    sCSR[pos] = s;
    dCSR[pos] = d;
}

// ---- per-position exp weights (CSR order), layer 1 (H=4) ------------------
__global__ __launch_bounds__(256) void edgew1_kernel(const int* __restrict__ sCSR,
                                                     const int* __restrict__ dCSR,
                                                     int Et,
                                                     const float* __restrict__ alS,
                                                     const float* __restrict__ alD,
                                                     float* __restrict__ wE) {
    int i = blockIdx.x * 256 + threadIdx.x;
    if (i >= Et) return;
    int s = sCSR[i], d = dCSR[i];
    float4 as = *(const float4*)(alS + (size_t)s * 4);
    float4 ad = *(const float4*)(alD + (size_t)d * 4);
    float4 w;
    float t;
    t = as.x + ad.x; w.x = expf(LRELU(t));
    t = as.y + ad.y; w.y = expf(LRELU(t));
    t = as.z + ad.z; w.z = expf(LRELU(t));
    t = as.w + ad.w; w.w = expf(LRELU(t));
    *(float4*)(wE + (size_t)i * 4) = w;
}

// ---- layer-1 aggregate -> xaggF (B-frag order), 4-deep gather pipeline ----
__global__ __launch_bounds__(256) void aggx_kernel(const u16* __restrict__ xbf,
                                                   const int* __restrict__ sCSR,
                                                   const int* __restrict__ offs,
                                                   const float* __restrict__ wE,
                                                   u16* __restrict__ xaggF, int Nn) {
    int n = blockIdx.x * 4 + (threadIdx.x >> 6);
    int t = threadIdx.x & 63;
    if (n >= Nn) return;
    float a0x = 0.f, a0y = 0.f, a1x = 0.f, a1y = 0.f;
    float a2x = 0.f, a2y = 0.f, a3x = 0.f, a3y = 0.f;
    float ws0 = 0.f, ws1 = 0.f, ws2 = 0.f, ws3 = 0.f;
    int s0 = offs[n], s1 = offs[n + 1];
    int i = s0;
    for (; i + 3 < s1; i += 4) {
        int sn[4]; float4 w[4]; u32 u[4];
#pragma unroll
        for (int j = 0; j < 4; ++j) {
            sn[j] = sCSR[i + j];
            w[j] = *(const float4*)(wE + (size_t)(i + j) * 4);
        }
#pragma unroll
        for (int j = 0; j < 4; ++j)
            u[j] = *(const u32*)(xbf + (size_t)sn[j] * 128 + t * 2);
#pragma unroll
        for (int j = 0; j < 4; ++j) {
            float xlo = __uint_as_float(u[j] << 16);
            float xhi = __uint_as_float(u[j] & 0xffff0000u);
            a0x += w[j].x * xlo; a0y += w[j].x * xhi;
            a1x += w[j].y * xlo; a1y += w[j].y * xhi;
            a2x += w[j].z * xlo; a2y += w[j].z * xhi;
            a3x += w[j].w * xlo; a3y += w[j].w * xhi;
            ws0 += w[j].x; ws1 += w[j].y; ws2 += w[j].z; ws3 += w[j].w;
        }
    }
    for (; i < s1; ++i) {
        int sn = sCSR[i];
        float4 w = *(const float4*)(wE + (size_t)i * 4);
        u32 u = *(const u32*)(xbf + (size_t)sn * 128 + t * 2);
        float xlo = __uint_as_float(u << 16);
        float xhi = __uint_as_float(u & 0xffff0000u);
        a0x += w.x * xlo; a0y += w.x * xhi;
        a1x += w.y * xlo; a1y += w.y * xhi;
        a2x += w.z * xlo; a2y += w.z * xhi;
        a3x += w.w * xlo; a3y += w.w * xhi;
        ws0 += w.x; ws1 += w.y; ws2 += w.z; ws3 += w.w;
    }
    float i0 = 1.f / ws0, i1 = 1.f / ws1, i2 = 1.f / ws2, i3 = 1.f / ws3;
    // fragment-order address: f0 = 2t
    int group = n >> 4, lrow = n & 15;
    int f0 = t * 2;
    int sl = f0 >> 5;
    int kg = (f0 >> 2) & 3;
    int j0 = ((f0 >> 4) & 1) * 4 + (f0 & 3);
    size_t base = ((size_t)group * 16 + sl) * 512 + (size_t)(kg * 16 + lrow) * 8 + j0;
    *(u32*)(xaggF + base + 0 * 2048) = packbf(a0x * i0, a0y * i0);
    *(u32*)(xaggF + base + 1 * 2048) = packbf(a1x * i1, a1y * i1);
    *(u32*)(xaggF + base + 2 * 2048) = packbf(a2x * i2, a2y * i2);
    *(u32*)(xaggF + base + 3 * 2048) = packbf(a3x * i3, a3y * i3);
}

// ---- layer-1 GEMM: out1F = elu(xaggF @ W1 + b1), fragment-native ----------
__global__ __launch_bounds__(64) void gemm1_mfma(const u16* __restrict__ xaggF,
                                                 const u16* __restrict__ W1f,
                                                 const float* __restrict__ b1,
                                                 u16* __restrict__ out1F) {
    int l = threadIdx.x;
    int head = blockIdx.y;
    int g0 = blockIdx.x * 2;
    int kg = l >> 4;

    bf16x8 xf[2][4];
#pragma unroll
    for (int g = 0; g < 2; ++g) {
        const u16* p = xaggF + ((size_t)(g0 + g) * 16 + head * 4) * 512 + l * 8;
#pragma unroll
        for (int s = 0; s < 4; ++s) xf[g][s] = *(const bf16x8*)(p + s * 512);
    }

    const u16* wbase = W1f + (size_t)head * 32 * 512 + l * 8;

#pragma unroll
    for (int cbp = 0; cbp < 4; ++cbp) {
        bf16x8 op0, op1;
#pragma unroll
        for (int par = 0; par < 2; ++par) {
            int cb = cbp * 2 + par;
            bf16x8 wf[4];
#pragma unroll
            for (int s = 0; s < 4; ++s)
                wf[s] = *(const bf16x8*)(wbase + (size_t)(cb * 4 + s) * 512);
            float4 bias = *(const float4*)(b1 + head * 128 + cb * 16 + kg * 4);
#pragma unroll
            for (int g = 0; g < 2; ++g) {
                f32x4 acc = {0.f, 0.f, 0.f, 0.f};
#pragma unroll
                for (int s = 0; s < 4; ++s)
                    acc = __builtin_amdgcn_mfma_f32_16x16x32_bf16(wf[s], xf[g][s],
                                                                  acc, 0, 0, 0);
                float v0 = ELU(acc[0] + bias.x);
                float v1 = ELU(acc[1] + bias.y);
                float v2 = ELU(acc[2] + bias.z);
                float v3 = ELU(acc[3] + bias.w);
                bf16x8& op = g ? op1 : op0;
                if (par == 0) {
                    op[0] = (short)f2bf(v0); op[1] = (short)f2bf(v1);
                    op[2] = (short)f2bf(v2); op[3] = (short)f2bf(v3);
                } else {
                    op[4] = (short)f2bf(v0); op[5] = (short)f2bf(v1);
                    op[6] = (short)f2bf(v2); op[7] = (short)f2bf(v3);
                }
            }
        }
#pragma unroll
        for (int g = 0; g < 2; ++g) {
            u16* op = out1F + ((size_t)(g0 + g) * 16 + head * 4 + cbp) * 512 + l * 8;
            *(bf16x8*)op = g ? op1 : op0;
        }
    }
}

// ---- layer-2 GEMM + fused al2, fragment-native ----------------------------
__global__ __launch_bounds__(64) void gemm2_mfma(const u16* __restrict__ out1F,
                                                 const u16* __restrict__ W2f,
                                                 const float* __restrict__ a_s2,
                                                 const float* __restrict__ a_d2,
                                                 u16* __restrict__ h2bf,
                                                 float* __restrict__ alS,
                                                 float* __restrict__ alD, int M) {
    int l = threadIdx.x;
    int g = blockIdx.x;
    int lrow = l & 15, kg = l >> 4;
    int node = g * 16 + lrow;

    const u16* xp = out1F + (size_t)g * 16 * 512 + l * 8;
    bf16x8 xf[16];
#pragma unroll
    for (int s = 0; s < 16; ++s) xf[s] = *(const bf16x8*)(xp + s * 512);

    const u16* wp = W2f + l * 8;
    float ps = 0.f, pd = 0.f;
#pragma unroll
    for (int c2 = 0; c2 < 4; ++c2) {
        int c0 = c2 * 16;
        f32x4 acc = {0.f, 0.f, 0.f, 0.f};
#pragma unroll
        for (int s = 0; s < 16; ++s) {
            bf16x8 wf = *(const bf16x8*)(wp + (size_t)(c2 * 16 + s) * 512);
            acc = __builtin_amdgcn_mfma_f32_16x16x32_bf16(wf, xf[s], acc, 0, 0, 0);
        }
        float4 as = *(const float4*)(a_s2 + c0 + kg * 4);
        float4 ad = *(const float4*)(a_d2 + c0 + kg * 4);
        ps += acc[0] * as.x + acc[1] * as.y + acc[2] * as.z + acc[3] * as.w;
        pd += acc[0] * ad.x + acc[1] * ad.y + acc[2] * ad.z + acc[3] * ad.w;
        if (node < M) {
            ushort4 o;
            o.x = f2bf(acc[0]); o.y = f2bf(acc[1]);
            o.z = f2bf(acc[2]); o.w = f2bf(acc[3]);
            *(ushort4*)(h2bf + (size_t)node * 64 + c0 + kg * 4) = o;
        }
    }
    ps += __shfl_xor(ps, 16); ps += __shfl_xor(ps, 32);
    pd += __shfl_xor(pd, 16); pd += __shfl_xor(pd, 32);
    if (kg == 0 && node < M) { alS[node] = ps; alD[node] = pd; }
}

__global__ __launch_bounds__(256) void edgew2_kernel(const int* __restrict__ sCSR,
                                                     const int* __restrict__ dCSR,
                                                     int Et,
                                                     const float* __restrict__ alS,
                                                     const float* __restrict__ alD,
                                                     float* __restrict__ wE) {
    int i = blockIdx.x * 256 + threadIdx.x;
    if (i >= Et) return;
    int s = sCSR[i], d = dCSR[i];
    float t = alS[s] + alD[d];
    wE[i] = expf(LRELU(t));
}

// ---- layer-2 aggregate, 4-deep gather pipeline ----------------------------
__global__ __launch_bounds__(256) void agg2_kernel(const u16* __restrict__ h2bf,
                                                   const int* __restrict__ sCSR,
                                                   const int* __restrict__ offs,
                                                   const float* __restrict__ wE,
                                                   const float* __restrict__ b2,
                                                   float* __restrict__ out2, int Nn) {
    int n = blockIdx.x * 4 + (threadIdx.x >> 6);
    int f = threadIdx.x & 63;
    if (n >= Nn) return;
    float acc = 0.f, wsum = 0.f;
    int s0 = offs[n], s1 = offs[n + 1];
    int i = s0;
    for (; i + 3 < s1; i += 4) {
        int sn[4]; float w[4]; u16 hv[4];
#pragma unroll
        for (int j = 0; j < 4; ++j) { sn[j] = sCSR[i + j]; w[j] = wE[i + j]; }
#pragma unroll
        for (int j = 0; j < 4; ++j) hv[j] = h2bf[(size_t)sn[j] * 64 + f];
#pragma unroll
        for (int j = 0; j < 4; ++j) {
            wsum += w[j];
            acc += w[j] * bf2f(hv[j]);
        }
    }
    for (; i < s1; ++i) {
        int sn = sCSR[i];
        float w = wE[i];
        wsum += w;
        acc += w * bf2f(h2bf[(size_t)sn * 64 + f]);
    }
    float v = acc / wsum + b2[f];
    out2[(size_t)n * 64 + f] = ELU(v);
}

// ---------------- pool + head ----------------------------------------------
__device__ __forceinline__ int lower_bound_i(const int* arr, int n, int key) {
    int lo = 0, hi = n;
    while (lo < hi) {
        int mid = (lo + hi) >> 1;
        if (arr[mid] < key) lo = mid + 1; else hi = mid;
    }
    return lo;
}

__global__ __launch_bounds__(64) void pool_kernel(const float* __restrict__ h2,
                                                  const int* __restrict__ batch,
                                                  int Nn, float* __restrict__ pooled) {
    int g = blockIdx.x;
    __shared__ int sh[2];
    if (threadIdx.x == 0) sh[0] = lower_bound_i(batch, Nn, g);
    if (threadIdx.x == 1) sh[1] = lower_bound_i(batch, Nn, g + 1);
    __syncthreads();
    int s0 = sh[0], s1 = sh[1];
    float sum = 0.f;
    for (int i = s0; i < s1; ++i) sum += h2[(size_t)i * 64 + threadIdx.x];
    float cnt = (float)((s1 - s0) > 1 ? (s1 - s0) : 1);
    pooled[(size_t)g * 64 + threadIdx.x] = sum / cnt;
}

__global__ __launch_bounds__(64) void fc_kernel(const float* __restrict__ pooled,
                                                const float* __restrict__ w1,
                                                const float* __restrict__ bb1,
                                                const float* __restrict__ w2,
                                                const float* __restrict__ bb2,
                                                float* __restrict__ out) {
    int g = blockIdx.x;
    __shared__ float p[64];
    __shared__ float hid[32];
    int t = threadIdx.x;
    p[t] = pooled[(size_t)g * 64 + t];
    __syncthreads();
    if (t < 32) {
        float a = bb1[t];
#pragma unroll
        for (int k = 0; k < 64; ++k) a += p[k] * w1[k * 32 + t];
        hid[t] = a > 0.f ? a : 0.f;
    }
    __syncthreads();
    if (t == 0) {
        float a = bb2[0];
#pragma unroll
        for (int j = 0; j < 32; ++j) a += hid[j] * w2[j];
        out[g] = 1.0f / (1.0f + expf(-a));
    }
}

// ---------------------------------------------------------------------------
extern "C" void kernel_launch(void* const* d_in, const int* in_sizes, int n_in,
                              void* d_out, int out_size, void* d_ws, size_t ws_size,
                              hipStream_t stream) {
    const float* x      = (const float*)d_in[0];
    const int*   ei     = (const int*)d_in[1];
    const int*   batch  = (const int*)d_in[2];
    const float* W1     = (const float*)d_in[3];
    const float* a_src1 = (const float*)d_in[4];
    const float* a_dst1 = (const float*)d_in[5];
    const float* b1     = (const float*)d_in[6];
    const float* W2     = (const float*)d_in[7];
    const float* a_src2 = (const float*)d_in[8];
    const float* a_dst2 = (const float*)d_in[9];
    const float* b2     = (const float*)d_in[10];
    const float* fcw1   = (const float*)d_in[11];
    const float* fcb1   = (const float*)d_in[12];
    const float* fcw2   = (const float*)d_in[13];
    const float* fcb2   = (const float*)d_in[14];
    float* out = (float*)d_out;

    const int Nn = in_sizes[0] / 128;   // 25000
    const int E  = in_sizes[1] / 2;     // 400000
    const int Et = E + Nn;
    const int NG = out_size;            // 512
    const int* srcA = ei;
    const int* dstA = ei + E;

    const int ngroups = (Nn + 15) / 16;          // 1563
    const int ngp = (ngroups + 1) & ~1;          // padded even

    char* base = (char*)d_ws;
    size_t off = 0;
    auto alloc = [&](size_t bytes) -> void* {
        void* p = base + off;
        off += (bytes + 255) & ~(size_t)255;
        return p;
    };
    u16*   xbf    = (u16*)alloc((size_t)Nn * 128 * 2);
    u16*   xaggF  = (u16*)alloc((size_t)ngp * 16 * 512 * 2);   // B-frag order
    u16*   out1F  = (u16*)alloc((size_t)ngp * 16 * 512 * 2);   // B-frag order
    u16*   h2bf   = (u16*)alloc((size_t)Nn * 64 * 2);
    float* out2   = (float*)alloc((size_t)Nn * 64 * 4);
    u16*   W1f    = (u16*)alloc(65536 * 2);
    u16*   W2f    = (u16*)alloc(32768 * 2);
    float* Wa     = (float*)alloc(128 * 8 * 4);
    float* alS1   = (float*)alloc((size_t)Nn * 4 * 4);
    float* alD1   = (float*)alloc((size_t)Nn * 4 * 4);
    float* alS2   = (float*)alloc((size_t)Nn * 4);
    float* alD2   = (float*)alloc((size_t)Nn * 4);
    float* wE1    = (float*)alloc((size_t)Et * 4 * 4);
    float* wE2    = (float*)alloc((size_t)Et * 4);
    int*   deg    = (int*)alloc((size_t)2 * Nn * 4);
    int*   fill   = deg + Nn;
    int*   offs   = (int*)alloc((size_t)(Nn + 1) * 4);
    int*   bsum   = (int*)alloc(64 * 4);
    int*   sCSR   = (int*)alloc((size_t)Et * 4);
    int*   dCSR   = (int*)alloc((size_t)Et * 4);
    float* pooled = (float*)alloc((size_t)NG * 64 * 4);
    (void)ws_size; (void)n_in;

    const int EB = (Et + 255) / 256;
    const int NB = (Nn + 2047) / 2048;

    // ---- weight prep + fused x prep ----
    castw_kernel<<<(65536 + 32768 + 255) / 256, 256, 0, stream>>>(W1, W2, W1f, W2f);
    wa_kernel<<<4, 256, 0, stream>>>(W1, a_src1, a_dst1, Wa);
    prep_x<<<(Nn + 3) / 4, 256, 0, stream>>>(x, Wa, xbf, alS1, alD1, Nn);

    // ---- CSR build ----
    hipMemsetAsync(deg, 0, sizeof(int) * 2 * Nn, stream);
    count_kernel<<<EB, 256, 0, stream>>>(dstA, E, Nn, deg);
    scanA_kernel<<<NB, 256, 0, stream>>>(deg, offs, bsum, Nn);
    scanB_kernel<<<1, 64, 0, stream>>>(bsum, NB);
    scanC_kernel<<<(Nn + 255) / 256, 256, 0, stream>>>(offs, bsum, Nn);
    scatter_kernel<<<EB, 256, 0, stream>>>(srcA, dstA, E, Nn, offs, fill, sCSR, dCSR);

    // ---- layer 1 ----
    edgew1_kernel<<<EB, 256, 0, stream>>>(sCSR, dCSR, Et, alS1, alD1, wE1);
    aggx_kernel<<<(Nn + 3) / 4, 256, 0, stream>>>(xbf, sCSR, offs, wE1, xaggF, Nn);
    dim3 g1(ngp / 2, 4);
    gemm1_mfma<<<g1, 64, 0, stream>>>(xaggF, W1f, b1, out1F);

    // ---- layer 2 (al2 fused into gemm2) ----
    gemm2_mfma<<<ngroups, 64, 0, stream>>>(out1F, W2f, a_src2, a_dst2,
                                           h2bf, alS2, alD2, Nn);
    edgew2_kernel<<<EB, 256, 0, stream>>>(sCSR, dCSR, Et, alS2, alD2, wE2);
    agg2_kernel<<<(Nn + 3) / 4, 256, 0, stream>>>(h2bf, sCSR, offs, wE2, b2, out2, Nn);

    // ---- pool + head ----
    pool_kernel<<<NG, 64, 0, stream>>>(out2, batch, Nn, pooled);
    fc_kernel<<<NG, 64, 0, stream>>>(pooled, fcw1, fcb1, fcw2, fcb2, out);
}

// Round 10
// 189.852 us; speedup vs baseline: 1.5438x; 1.1101x over previous
//
#include <hip/hip_runtime.h>
#include <hip/hip_bf16.h>

// ---------------------------------------------------------------------------
// GAT (2 layers) + mean pool + MLP head.
// R8->R9: (1) aggx/agg2 gathers widened -- wave split into two 32-lane halves
// handling alternate edges (per-edge gather width doubles, 8 rows in flight
// with the 4-deep unroll); halves combined via shfl_xor(32). (2) launch-tail
// fusion: castw+wa -> prep_w, edgew1 folded into scatter, pool+fc -> poolfc.
// Fragment-native GEMM pipeline unchanged from R7/R8.
// ---------------------------------------------------------------------------

typedef unsigned short u16;
typedef unsigned int u32;
typedef __attribute__((ext_vector_type(8))) short bf16x8;
typedef __attribute__((ext_vector_type(4))) float f32x4;

#define LRELU(v) ((v) > 0.0f ? (v) : 0.2f * (v))
#define ELU(v)   ((v) > 0.0f ? (v) : expm1f(v))

__device__ __forceinline__ u16 f2bf(float f) {
    union { float f; u32 u; } c; c.f = f;
    u32 u = c.u;
    u32 r = (u + 0x7fffu + ((u >> 16) & 1u)) >> 16;
    return (u16)r;
}
__device__ __forceinline__ float bf2f(u16 h) {
    return __uint_as_float(((u32)h) << 16);
}

// ---- fused weight prep: W1f/W2f (fragment order) + Wa fold ----------------
__global__ __launch_bounds__(256) void prep_w(const float* __restrict__ W1,
                                              const float* __restrict__ W2,
                                              const float* __restrict__ a_s,
                                              const float* __restrict__ a_d,
                                              u16* __restrict__ W1f,
                                              u16* __restrict__ W2f,
                                              float* __restrict__ Wa) {
    int b = blockIdx.x;
    if (b < 384) {
        int idx = b * 256 + threadIdx.x;
        if (idx < 65536) {
            int fid = idx >> 9, l = (idx >> 3) & 63, j = idx & 7;
            int head = fid >> 5, cb = (fid >> 2) & 7, s = fid & 3;
            int col = head * 128 + cb * 16 + (l & 15);
            int k = s * 32 + 16 * (j >> 2) + 4 * (l >> 4) + (j & 3);
            W1f[idx] = f2bf(W1[(size_t)k * 512 + col]);
        } else {
            int i2 = idx - 65536;
            int fid = i2 >> 9, l = (i2 >> 3) & 63, j = i2 & 7;
            int c2 = fid >> 4, s = fid & 15;
            int col = c2 * 16 + (l & 15);
            int k = s * 32 + 16 * (j >> 2) + 4 * (l >> 4) + (j & 3);
            W2f[i2] = f2bf(W2[(size_t)k * 64 + col]);
        }
    } else {
        int idx = (b - 384) * 256 + threadIdx.x;   // 0..1023
        int k = idx >> 3, j = idx & 7, h = j & 3;
        const float* a = (j < 4) ? (a_s + h * 128) : (a_d + h * 128);
        const float* wrow = W1 + (size_t)k * 512 + h * 128;
        float s = 0.f;
#pragma unroll 8
        for (int o = 0; o < 128; ++o) s += wrow[o] * a[o];
        Wa[k * 8 + j] = s;
    }
}

// ---- prep_x: xbf = bf16(x)  AND  alS1/alD1 = x @ Wa  (fused, one x pass) --
__global__ __launch_bounds__(256) void prep_x(const float* __restrict__ x,
                                              const float* __restrict__ Wa,
                                              u16* __restrict__ xbf,
                                              float* __restrict__ alS,
                                              float* __restrict__ alD, int Nn) {
    int lane = threadIdx.x & 63;
    int wave = threadIdx.x >> 6;
    float4 ls = *(const float4*)(Wa + lane * 8);
    float4 ld = *(const float4*)(Wa + lane * 8 + 4);
    float4 hs = *(const float4*)(Wa + (lane + 64) * 8);
    float4 hd = *(const float4*)(Wa + (lane + 64) * 8 + 4);
    int n = blockIdx.x * 4 + wave;
    if (n >= Nn) return;
    float x0 = x[(size_t)n * 128 + lane];
    float x1 = x[(size_t)n * 128 + lane + 64];
    xbf[(size_t)n * 128 + lane]      = f2bf(x0);
    xbf[(size_t)n * 128 + lane + 64] = f2bf(x1);
    float r0 = x0 * ls.x + x1 * hs.x;
    float r1 = x0 * ls.y + x1 * hs.y;
    float r2 = x0 * ls.z + x1 * hs.z;
    float r3 = x0 * ls.w + x1 * hs.w;
    float r4 = x0 * ld.x + x1 * hd.x;
    float r5 = x0 * ld.y + x1 * hd.y;
    float r6 = x0 * ld.z + x1 * hd.z;
    float r7 = x0 * ld.w + x1 * hd.w;
#pragma unroll
    for (int off = 32; off; off >>= 1) {
        r0 += __shfl_down(r0, off); r1 += __shfl_down(r1, off);
        r2 += __shfl_down(r2, off); r3 += __shfl_down(r3, off);
        r4 += __shfl_down(r4, off); r5 += __shfl_down(r5, off);
        r6 += __shfl_down(r6, off); r7 += __shfl_down(r7, off);
    }
    if (lane == 0) {
        *(float4*)(alS + (size_t)n * 4) = make_float4(r0, r1, r2, r3);
        *(float4*)(alD + (size_t)n * 4) = make_float4(r4, r5, r6, r7);
    }
}

// ---------------- CSR build ------------------------------------------------
__global__ __launch_bounds__(256) void count_kernel(const int* __restrict__ dst,
                                                    int E, int Nn, int* __restrict__ deg) {
    int e = blockIdx.x * 256 + threadIdx.x;
    if (e >= E + Nn) return;
    int d = (e < E) ? dst[e] : (e - E);
    atomicAdd(&deg[d], 1);
}

__global__ __launch_bounds__(256) void scanA_kernel(const int* __restrict__ deg,
                                                    int* __restrict__ offs,
                                                    int* __restrict__ bsum, int n) {
    __shared__ int sh[256];
    int b = blockIdx.x, t = threadIdx.x;
    int base = b * 2048 + t * 8;
    int v[8]; int s = 0;
#pragma unroll
    for (int j = 0; j < 8; ++j) { int i = base + j; v[j] = (i < n) ? deg[i] : 0; s += v[j]; }
    sh[t] = s;
    __syncthreads();
    for (int off = 1; off < 256; off <<= 1) {
        int u = (t >= off) ? sh[t - off] : 0;
        __syncthreads();
        sh[t] += u;
        __syncthreads();
    }
    int run = sh[t] - s;
    if (t == 255) bsum[b] = sh[255];
#pragma unroll
    for (int j = 0; j < 8; ++j) {
        run += v[j];
        int i = base + j;
        if (i < n) offs[i + 1] = run;
    }
}

__global__ __launch_bounds__(64) void scanB_kernel(int* __restrict__ bsum, int nb) {
    int t = threadIdx.x;
    int v = (t < nb) ? bsum[t] : 0;
#pragma unroll
    for (int off = 1; off < 64; off <<= 1) {
        int u = __shfl_up(v, off);
        if (t >= off) v += u;
    }
    if (t < nb) bsum[t] = v;
}

__global__ __launch_bounds__(256) void scanC_kernel(int* __restrict__ offs,
                                                    const int* __restrict__ bsum, int n) {
    int i = blockIdx.x * 256 + threadIdx.x;
    if (i == 0) offs[0] = 0;
    if (i >= n) return;
    int b = i >> 11;
    if (b > 0) offs[i + 1] += bsum[b - 1];
}

// scatter edges into CSR order + fused layer-1 edge weights
__global__ __launch_bounds__(256) void scatter_kernel(const int* __restrict__ src,
                                                      const int* __restrict__ dst,
                                                      int E, int Nn,
                                                      const int* __restrict__ offs,
                                                      int* __restrict__ fill,
                                                      const float* __restrict__ alS,
                                                      const float* __restrict__ alD,
                                                      int* __restrict__ sCSR,
                                                      int* __restrict__ dCSR,
                                                      float* __restrict__ wE1) {
    int e = blockIdx.x * 256 + threadIdx.x;
    if (e >= E + Nn) return;
    int s = (e < E) ? src[e] : (e - E);
    int d = (e < E) ? dst[e] : (e - E);
    int pos = offs[d] + atomicAdd(&fill[d], 1);
    sCSR[pos] = s;
    dCSR[pos] = d;
    float4 as = *(const float4*)(alS + (size_t)s * 4);
    float4 ad = *(const float4*)(alD + (size_t)d * 4);
    float4 w;
    float t;
    t = as.x + ad.x; w.x = expf(LRELU(t));
    t = as.y + ad.y; w.y = expf(LRELU(t));
    t = as.z + ad.z; w.z = expf(LRELU(t));
    t = as.w + ad.w; w.w = expf(LRELU(t));
    *(float4*)(wE1 + (size_t)pos * 4) = w;
}

// ---- layer-1 aggregate -> xaggF (B-frag order), half-wave edge split ------
// Lanes split into halves (l>>5): each half owns alternate CSR entries with
// ushort4 (4-feat) gathers; 4-deep unroll -> 8 rows in flight per wave.
__global__ __launch_bounds__(256) void aggx_kernel(const u16* __restrict__ xbf,
                                                   const int* __restrict__ sCSR,
                                                   const int* __restrict__ offs,
                                                   const float* __restrict__ wE,
                                                   u16* __restrict__ xaggF, int Nn) {
    int n = blockIdx.x * 4 + (threadIdx.x >> 6);
    int l = threadIdx.x & 63;
    if (n >= Nn) return;
    int half = l >> 5;
    int fl = (l & 31) * 4;        // feats fl..fl+3
    float a0[4] = {0.f, 0.f, 0.f, 0.f};
    float a1[4] = {0.f, 0.f, 0.f, 0.f};
    float a2[4] = {0.f, 0.f, 0.f, 0.f};
    float a3[4] = {0.f, 0.f, 0.f, 0.f};
    float ws0 = 0.f, ws1 = 0.f, ws2 = 0.f, ws3 = 0.f;
    int s0 = offs[n], s1 = offs[n + 1];
    int i = s0 + half;
    for (; i + 6 < s1; i += 8) {
        int sn[4]; float4 w[4]; ushort4 u[4];
#pragma unroll
        for (int j = 0; j < 4; ++j) {
            int idx = i + 2 * j;
            sn[j] = sCSR[idx];
            w[j] = *(const float4*)(wE + (size_t)idx * 4);
        }
#pragma unroll
        for (int j = 0; j < 4; ++j)
            u[j] = *(const ushort4*)(xbf + (size_t)sn[j] * 128 + fl);
#pragma unroll
        for (int j = 0; j < 4; ++j) {
            float xv[4] = {bf2f(u[j].x), bf2f(u[j].y), bf2f(u[j].z), bf2f(u[j].w)};
#pragma unroll
            for (int q = 0; q < 4; ++q) {
                a0[q] += w[j].x * xv[q];
                a1[q] += w[j].y * xv[q];
                a2[q] += w[j].z * xv[q];
                a3[q] += w[j].w * xv[q];
            }
            ws0 += w[j].x; ws1 += w[j].y; ws2 += w[j].z; ws3 += w[j].w;
        }
    }
    for (; i < s1; i += 2) {
        int sn = sCSR[i];
        float4 w = *(const float4*)(wE + (size_t)i * 4);
        ushort4 u = *(const ushort4*)(xbf + (size_t)sn * 128 + fl);
        float xv[4] = {bf2f(u.x), bf2f(u.y), bf2f(u.z), bf2f(u.w)};
#pragma unroll
        for (int q = 0; q < 4; ++q) {
            a0[q] += w.x * xv[q];
            a1[q] += w.y * xv[q];
            a2[q] += w.z * xv[q];
            a3[q] += w.w * xv[q];
        }
        ws0 += w.x; ws1 += w.y; ws2 += w.z; ws3 += w.w;
    }
    // combine the two halves
#pragma unroll
    for (int q = 0; q < 4; ++q) {
        a0[q] += __shfl_xor(a0[q], 32);
        a1[q] += __shfl_xor(a1[q], 32);
        a2[q] += __shfl_xor(a2[q], 32);
        a3[q] += __shfl_xor(a3[q], 32);
    }
    ws0 += __shfl_xor(ws0, 32); ws1 += __shfl_xor(ws1, 32);
    ws2 += __shfl_xor(ws2, 32); ws3 += __shfl_xor(ws3, 32);
    if (half == 0) {
        float i0 = 1.f / ws0, i1 = 1.f / ws1, i2 = 1.f / ws2, i3 = 1.f / ws3;
        int group = n >> 4, lrow = n & 15;
        int sl = fl >> 5;
        int kg = (fl >> 2) & 3;
        int j0 = ((fl >> 4) & 1) * 4;
        size_t base = ((size_t)group * 16 + sl) * 512 + (size_t)(kg * 16 + lrow) * 8 + j0;
        ushort4 o;
        o.x = f2bf(a0[0] * i0); o.y = f2bf(a0[1] * i0);
        o.z = f2bf(a0[2] * i0); o.w = f2bf(a0[3] * i0);
        *(ushort4*)(xaggF + base + 0 * 2048) = o;
        o.x = f2bf(a1[0] * i1); o.y = f2bf(a1[1] * i1);
        o.z = f2bf(a1[2] * i1); o.w = f2bf(a1[3] * i1);
        *(ushort4*)(xaggF + base + 1 * 2048) = o;
        o.x = f2bf(a2[0] * i2); o.y = f2bf(a2[1] * i2);
        o.z = f2bf(a2[2] * i2); o.w = f2bf(a2[3] * i2);
        *(ushort4*)(xaggF + base + 2 * 2048) = o;
        o.x = f2bf(a3[0] * i3); o.y = f2bf(a3[1] * i3);
        o.z = f2bf(a3[2] * i3); o.w = f2bf(a3[3] * i3);
        *(ushort4*)(xaggF + base + 3 * 2048) = o;
    }
}

// ---- layer-1 GEMM: out1F = elu(xaggF @ W1 + b1), fragment-native ----------
__global__ __launch_bounds__(64) void gemm1_mfma(const u16* __restrict__ xaggF,
                                                 const u16* __restrict__ W1f,
                                                 const float* __restrict__ b1,
                                                 u16* __restrict__ out1F) {
    int l = threadIdx.x;
    int head = blockIdx.y;
    int g0 = blockIdx.x * 2;
    int kg = l >> 4;

    bf16x8 xf[2][4];
#pragma unroll
    for (int g = 0; g < 2; ++g) {
        const u16* p = xaggF + ((size_t)(g0 + g) * 16 + head * 4) * 512 + l * 8;
#pragma unroll
        for (int s = 0; s < 4; ++s) xf[g][s] = *(const bf16x8*)(p + s * 512);
    }

    const u16* wbase = W1f + (size_t)head * 32 * 512 + l * 8;

#pragma unroll
    for (int cbp = 0; cbp < 4; ++cbp) {
        bf16x8 op0, op1;
#pragma unroll
        for (int par = 0; par < 2; ++par) {
            int cb = cbp * 2 + par;
            bf16x8 wf[4];
#pragma unroll
            for (int s = 0; s < 4; ++s)
                wf[s] = *(const bf16x8*)(wbase + (size_t)(cb * 4 + s) * 512);
            float4 bias = *(const float4*)(b1 + head * 128 + cb * 16 + kg * 4);
#pragma unroll
            for (int g = 0; g < 2; ++g) {
                f32x4 acc = {0.f, 0.f, 0.f, 0.f};
#pragma unroll
                for (int s = 0; s < 4; ++s)
                    acc = __builtin_amdgcn_mfma_f32_16x16x32_bf16(wf[s], xf[g][s],
                                                                  acc, 0, 0, 0);
                float v0 = ELU(acc[0] + bias.x);
                float v1 = ELU(acc[1] + bias.y);
                float v2 = ELU(acc[2] + bias.z);
                float v3 = ELU(acc[3] + bias.w);
                bf16x8& op = g ? op1 : op0;
                if (par == 0) {
                    op[0] = (short)f2bf(v0); op[1] = (short)f2bf(v1);
                    op[2] = (short)f2bf(v2); op[3] = (short)f2bf(v3);
                } else {
                    op[4] = (short)f2bf(v0); op[5] = (short)f2bf(v1);
                    op[6] = (short)f2bf(v2); op[7] = (short)f2bf(v3);
                }
            }
        }
#pragma unroll
        for (int g = 0; g < 2; ++g) {
            u16* op = out1F + ((size_t)(g0 + g) * 16 + head * 4 + cbp) * 512 + l * 8;
            *(bf16x8*)op = g ? op1 : op0;
        }
    }
}

// ---- layer-2 GEMM + fused al2, fragment-native ----------------------------
__global__ __launch_bounds__(64) void gemm2_mfma(const u16* __restrict__ out1F,
                                                 const u16* __restrict__ W2f,
                                                 const float* __restrict__ a_s2,
                                                 const float* __restrict__ a_d2,
                                                 u16* __restrict__ h2bf,
                                                 float* __restrict__ alS,
                                                 float* __restrict__ alD, int M) {
    int l = threadIdx.x;
    int g = blockIdx.x;
    int lrow = l & 15, kg = l >> 4;
    int node = g * 16 + lrow;

    const u16* xp = out1F + (size_t)g * 16 * 512 + l * 8;
    bf16x8 xf[16];
#pragma unroll
    for (int s = 0; s < 16; ++s) xf[s] = *(const bf16x8*)(xp + s * 512);

    const u16* wp = W2f + l * 8;
    float ps = 0.f, pd = 0.f;
#pragma unroll
    for (int c2 = 0; c2 < 4; ++c2) {
        int c0 = c2 * 16;
        f32x4 acc = {0.f, 0.f, 0.f, 0.f};
#pragma unroll
        for (int s = 0; s < 16; ++s) {
            bf16x8 wf = *(const bf16x8*)(wp + (size_t)(c2 * 16 + s) * 512);
            acc = __builtin_amdgcn_mfma_f32_16x16x32_bf16(wf, xf[s], acc, 0, 0, 0);
        }
        float4 as = *(const float4*)(a_s2 + c0 + kg * 4);
        float4 ad = *(const float4*)(a_d2 + c0 + kg * 4);
        ps += acc[0] * as.x + acc[1] * as.y + acc[2] * as.z + acc[3] * as.w;
        pd += acc[0] * ad.x + acc[1] * ad.y + acc[2] * ad.z + acc[3] * ad.w;
        if (node < M) {
            ushort4 o;
            o.x = f2bf(acc[0]); o.y = f2bf(acc[1]);
            o.z = f2bf(acc[2]); o.w = f2bf(acc[3]);
            *(ushort4*)(h2bf + (size_t)node * 64 + c0 + kg * 4) = o;
        }
    }
    ps += __shfl_xor(ps, 16); ps += __shfl_xor(ps, 32);
    pd += __shfl_xor(pd, 16); pd += __shfl_xor(pd, 32);
    if (kg == 0 && node < M) { alS[node] = ps; alD[node] = pd; }
}

__global__ __launch_bounds__(256) void edgew2_kernel(const int* __restrict__ sCSR,
                                                     const int* __restrict__ dCSR,
                                                     int Et,
                                                     const float* __restrict__ alS,
                                                     const float* __restrict__ alD,
                                                     float* __restrict__ wE) {
    int i = blockIdx.x * 256 + threadIdx.x;
    if (i >= Et) return;
    int s = sCSR[i], d = dCSR[i];
    float t = alS[s] + alD[d];
    wE[i] = expf(LRELU(t));
}

// ---- layer-2 aggregate, half-wave edge split + 4-deep pipeline ------------
__global__ __launch_bounds__(256) void agg2_kernel(const u16* __restrict__ h2bf,
                                                   const int* __restrict__ sCSR,
                                                   const int* __restrict__ offs,
                                                   const float* __restrict__ wE,
                                                   const float* __restrict__ b2,
                                                   float* __restrict__ out2, int Nn) {
    int n = blockIdx.x * 4 + (threadIdx.x >> 6);
    int l = threadIdx.x & 63;
    if (n >= Nn) return;
    int half = l >> 5;
    int fl = (l & 31) * 2;        // feats fl, fl+1
    float ax = 0.f, ay = 0.f, ws = 0.f;
    int s0 = offs[n], s1 = offs[n + 1];
    int i = s0 + half;
    for (; i + 6 < s1; i += 8) {
        int sn[4]; float w[4]; u32 u[4];
#pragma unroll
        for (int j = 0; j < 4; ++j) {
            int idx = i + 2 * j;
            sn[j] = sCSR[idx];
            w[j] = wE[idx];
        }
#pragma unroll
        for (int j = 0; j < 4; ++j)
            u[j] = *(const u32*)(h2bf + (size_t)sn[j] * 64 + fl);
#pragma unroll
        for (int j = 0; j < 4; ++j) {
            ax += w[j] * __uint_as_float(u[j] << 16);
            ay += w[j] * __uint_as_float(u[j] & 0xffff0000u);
            ws += w[j];
        }
    }
    for (; i < s1; i += 2) {
        int sn = sCSR[i];
        float w = wE[i];
        u32 u = *(const u32*)(h2bf + (size_t)sn * 64 + fl);
        ax += w * __uint_as_float(u << 16);
        ay += w * __uint_as_float(u & 0xffff0000u);
        ws += w;
    }
    ax += __shfl_xor(ax, 32);
    ay += __shfl_xor(ay, 32);
    ws += __shfl_xor(ws, 32);
    if (half == 0) {
        float inv = 1.f / ws;
        float2 o;
        float v0 = ax * inv + b2[fl];
        float v1 = ay * inv + b2[fl + 1];
        o.x = ELU(v0);
        o.y = ELU(v1);
        *(float2*)(out2 + (size_t)n * 64 + fl) = o;
    }
}

// ---------------- fused pool + head ----------------------------------------
__device__ __forceinline__ int lower_bound_i(const int* arr, int n, int key) {
    int lo = 0, hi = n;
    while (lo < hi) {
        int mid = (lo + hi) >> 1;
        if (arr[mid] < key) lo = mid + 1; else hi = mid;
    }
    return lo;
}

__global__ __launch_bounds__(64) void poolfc_kernel(const float* __restrict__ h2,
                                                    const int* __restrict__ batch,
                                                    int Nn,
                                                    const float* __restrict__ w1,
                                                    const float* __restrict__ bb1,
                                                    const float* __restrict__ w2,
                                                    const float* __restrict__ bb2,
                                                    float* __restrict__ out) {
    int g = blockIdx.x;
    __shared__ int sh[2];
    __shared__ float p[64];
    __shared__ float hid[32];
    int t = threadIdx.x;
    if (t == 0) sh[0] = lower_bound_i(batch, Nn, g);
    if (t == 1) sh[1] = lower_bound_i(batch, Nn, g + 1);
    __syncthreads();
    int s0 = sh[0], s1 = sh[1];
    float sum = 0.f;
    for (int i = s0; i < s1; ++i) sum += h2[(size_t)i * 64 + t];
    float cnt = (float)((s1 - s0) > 1 ? (s1 - s0) : 1);
    p[t] = sum / cnt;
    __syncthreads();
    if (t < 32) {
        float a = bb1[t];
#pragma unroll
        for (int k = 0; k < 64; ++k) a += p[k] * w1[k * 32 + t];
        hid[t] = a > 0.f ? a : 0.f;
    }
    __syncthreads();
    if (t == 0) {
        float a = bb2[0];
#pragma unroll
        for (int j = 0; j < 32; ++j) a += hid[j] * w2[j];
        out[g] = 1.0f / (1.0f + expf(-a));
    }
}

// ---------------------------------------------------------------------------
extern "C" void kernel_launch(void* const* d_in, const int* in_sizes, int n_in,
                              void* d_out, int out_size, void* d_ws, size_t ws_size,
                              hipStream_t stream) {
    const float* x      = (const float*)d_in[0];
    const int*   ei     = (const int*)d_in[1];
    const int*   batch  = (const int*)d_in[2];
    const float* W1     = (const float*)d_in[3];
    const float* a_src1 = (const float*)d_in[4];
    const float* a_dst1 = (const float*)d_in[5];
    const float* b1     = (const float*)d_in[6];
    const float* W2     = (const float*)d_in[7];
    const float* a_src2 = (const float*)d_in[8];
    const float* a_dst2 = (const float*)d_in[9];
    const float* b2     = (const float*)d_in[10];
    const float* fcw1   = (const float*)d_in[11];
    const float* fcb1   = (const float*)d_in[12];
    const float* fcw2   = (const float*)d_in[13];
    const float* fcb2   = (const float*)d_in[14];
    float* out = (float*)d_out;

    const int Nn = in_sizes[0] / 128;   // 25000
    const int E  = in_sizes[1] / 2;     // 400000
    const int Et = E + Nn;
    const int NG = out_size;            // 512
    const int* srcA = ei;
    const int* dstA = ei + E;

    const int ngroups = (Nn + 15) / 16;          // 1563
    const int ngp = (ngroups + 1) & ~1;          // padded even

    char* base = (char*)d_ws;
    size_t off = 0;
    auto alloc = [&](size_t bytes) -> void* {
        void* p = base + off;
        off += (bytes + 255) & ~(size_t)255;
        return p;
    };
    u16*   xbf    = (u16*)alloc((size_t)Nn * 128 * 2);
    u16*   xaggF  = (u16*)alloc((size_t)ngp * 16 * 512 * 2);   // B-frag order
    u16*   out1F  = (u16*)alloc((size_t)ngp * 16 * 512 * 2);   // B-frag order
    u16*   h2bf   = (u16*)alloc((size_t)Nn * 64 * 2);
    float* out2   = (float*)alloc((size_t)Nn * 64 * 4);
    u16*   W1f    = (u16*)alloc(65536 * 2);
    u16*   W2f    = (u16*)alloc(32768 * 2);
    float* Wa     = (float*)alloc(128 * 8 * 4);
    float* alS1   = (float*)alloc((size_t)Nn * 4 * 4);
    float* alD1   = (float*)alloc((size_t)Nn * 4 * 4);
    float* alS2   = (float*)alloc((size_t)Nn * 4);
    float* alD2   = (float*)alloc((size_t)Nn * 4);
    float* wE1    = (float*)alloc((size_t)Et * 4 * 4);
    float* wE2    = (float*)alloc((size_t)Et * 4);
    int*   deg    = (int*)alloc((size_t)2 * Nn * 4);
    int*   fill   = deg + Nn;
    int*   offs   = (int*)alloc((size_t)(Nn + 1) * 4);
    int*   bsum   = (int*)alloc(64 * 4);
    int*   sCSR   = (int*)alloc((size_t)Et * 4);
    int*   dCSR   = (int*)alloc((size_t)Et * 4);
    (void)ws_size; (void)n_in;

    const int EB = (Et + 255) / 256;
    const int NB = (Nn + 2047) / 2048;

    // ---- weight prep (fused) + fused x prep ----
    prep_w<<<388, 256, 0, stream>>>(W1, W2, a_src1, a_dst1, W1f, W2f, Wa);
    prep_x<<<(Nn + 3) / 4, 256, 0, stream>>>(x, Wa, xbf, alS1, alD1, Nn);

    // ---- CSR build (scatter also emits layer-1 edge weights) ----
    hipMemsetAsync(deg, 0, sizeof(int) * 2 * Nn, stream);
    count_kernel<<<EB, 256, 0, stream>>>(dstA, E, Nn, deg);
    scanA_kernel<<<NB, 256, 0, stream>>>(deg, offs, bsum, Nn);
    scanB_kernel<<<1, 64, 0, stream>>>(bsum, NB);
    scanC_kernel<<<(Nn + 255) / 256, 256, 0, stream>>>(offs, bsum, Nn);
    scatter_kernel<<<EB, 256, 0, stream>>>(srcA, dstA, E, Nn, offs, fill,
                                           alS1, alD1, sCSR, dCSR, wE1);

    // ---- layer 1 ----
    aggx_kernel<<<(Nn + 3) / 4, 256, 0, stream>>>(xbf, sCSR, offs, wE1, xaggF, Nn);
    dim3 g1(ngp / 2, 4);
    gemm1_mfma<<<g1, 64, 0, stream>>>(xaggF, W1f, b1, out1F);

    // ---- layer 2 (al2 fused into gemm2) ----
    gemm2_mfma<<<ngroups, 64, 0, stream>>>(out1F, W2f, a_src2, a_dst2,
                                           h2bf, alS2, alD2, Nn);
    edgew2_kernel<<<EB, 256, 0, stream>>>(sCSR, dCSR, Et, alS2, alD2, wE2);
    agg2_kernel<<<(Nn + 3) / 4, 256, 0, stream>>>(h2bf, sCSR, offs, wE2, b2, out2, Nn);

    // ---- fused pool + head ----
    poolfc_kernel<<<NG, 64, 0, stream>>>(out2, batch, Nn, fcw1, fcb1, fcw2, fcb2, out);
}